// Round 7
// baseline (1203.733 us; speedup 1.0000x reference)
//
#include <hip/hip_runtime.h>
#include <math.h>

typedef short bf16x8 __attribute__((ext_vector_type(8)));
typedef float f32x4  __attribute__((ext_vector_type(4)));

__device__ __forceinline__ unsigned short f2bf(float x) {
    unsigned u = __float_as_uint(x);
    unsigned r = u + 0x7FFFu + ((u >> 16) & 1u);   // RNE
    return (unsigned short)(r >> 16);
}
__device__ __forceinline__ float bf2f(unsigned short b) {
    return __uint_as_float(((unsigned)b) << 16);
}

// ============ weight convert+transpose: Wt[n][k] = bf16(W[k][n]) ============
__global__ __launch_bounds__(256)
void wconv(const float* __restrict__ W, unsigned short* __restrict__ Wt, int K, int N)
{
    int id = blockIdx.x * 256 + threadIdx.x;
    if (id >= K * N) return;
    int n = id / K, k = id - n * K;
    Wt[(size_t)n * K + k] = f2bf(W[(size_t)k * N + n]);
}

// ============ MFMA GEMM, double-buffered LDS A, B direct-from-global ============
// A [M,K] (f32 or bf16); Wt bf16 [Ncols][K]. Tile 128x128, 4 waves 2x2, BK=64.
// out: bf16 tanh(A@W + bias).
template<bool ABF16>
__global__ __launch_bounds__(256)
void mfma_big(const void* __restrict__ A_, const unsigned short* __restrict__ Wt,
              const float* __restrict__ bias, unsigned short* __restrict__ out_bf,
              int M, int K, int Ncols)
{
    __shared__ __align__(16) unsigned short Al[2][128][72];   // 36.9 KB

    const int tid  = threadIdx.x;
    const int row0 = blockIdx.x * 128;
    const int col0 = blockIdx.y * 128;
    const int wv   = tid >> 6, lane = tid & 63;
    const int wr   = (wv >> 1) * 64, wc = (wv & 1) * 64;
    const int lr   = lane & 15;
    const int lk8  = (lane >> 4) * 8;

    const unsigned short* Ab = (const unsigned short*)A_;
    const float*          Af = (const float*)A_;

    f32x4 acc[4][4];
#pragma unroll
    for (int m = 0; m < 4; m++)
#pragma unroll
        for (int n = 0; n < 4; n++)
#pragma unroll
            for (int j = 0; j < 4; j++) acc[m][n][j] = 0.f;

    bf16x8 pre_b[4];
    float4 pre_f[8];
    const int T = K >> 6;

#define BIG_LOAD(t)                                                                  \
    do { int k0 = (t) << 6;                                                          \
        if (ABF16) {                                                                 \
            _Pragma("unroll")                                                        \
            for (int i = 0; i < 4; i++) {                                            \
                int f = i * 256 + tid; int r = f >> 3, k8 = (f & 7) << 3;            \
                bf16x8 v = {0,0,0,0,0,0,0,0};                                        \
                if (row0 + r < M) v = *(const bf16x8*)(Ab + (size_t)(row0 + r) * K + k0 + k8); \
                pre_b[i] = v;                                                        \
            }                                                                        \
        } else {                                                                     \
            _Pragma("unroll")                                                        \
            for (int i = 0; i < 8; i++) {                                            \
                int f = i * 256 + tid; int r = f >> 4, c4 = (f & 15) << 2;           \
                float4 a = make_float4(0.f, 0.f, 0.f, 0.f);                          \
                if (row0 + r < M) a = *(const float4*)(Af + (size_t)(row0 + r) * K + k0 + c4); \
                pre_f[i] = a;                                                        \
            }                                                                        \
        }                                                                            \
    } while (0)

#define BIG_STORE(buf)                                                               \
    do {                                                                             \
        if (ABF16) {                                                                 \
            _Pragma("unroll")                                                        \
            for (int i = 0; i < 4; i++) {                                            \
                int f = i * 256 + tid; int r = f >> 3, k8 = (f & 7) << 3;            \
                *(bf16x8*)&Al[buf][r][k8] = pre_b[i];                                \
            }                                                                        \
        } else {                                                                     \
            _Pragma("unroll")                                                        \
            for (int i = 0; i < 8; i++) {                                            \
                int f = i * 256 + tid; int r = f >> 4, c4 = (f & 15) << 2;           \
                float4 a = pre_f[i];                                                 \
                *(ushort4*)&Al[buf][r][c4] = make_ushort4(f2bf(a.x), f2bf(a.y), f2bf(a.z), f2bf(a.w)); \
            }                                                                        \
        }                                                                            \
    } while (0)

    BIG_LOAD(0);
    BIG_STORE(0);

    for (int t = 0; t < T; t++) {
        __syncthreads();                       // Al[t&1] ready
        if (t + 1 < T) BIG_LOAD(t + 1);        // prefetch next tile to regs (hidden)
        const int cur = t & 1;
        const int kbase = t << 6;
#pragma unroll
        for (int kk = 0; kk < 64; kk += 32) {
            bf16x8 af[4], bfr[4];
#pragma unroll
            for (int m = 0; m < 4; m++) af[m] = *(const bf16x8*)&Al[cur][wr + m * 16 + lr][kk + lk8];
#pragma unroll
            for (int n = 0; n < 4; n++)
                bfr[n] = *(const bf16x8*)(Wt + (size_t)(col0 + wc + n * 16 + lr) * K + kbase + kk + lk8);
#pragma unroll
            for (int m = 0; m < 4; m++)
#pragma unroll
                for (int n = 0; n < 4; n++)
                    acc[m][n] = __builtin_amdgcn_mfma_f32_16x16x32_bf16(af[m], bfr[n], acc[m][n], 0, 0, 0);
        }
        if (t + 1 < T) {
            __syncthreads();                   // all reads of Al[(t+1)&1] done (at t-1)
            BIG_STORE((t + 1) & 1);
        }
    }

    const int rbase = (lane >> 4) * 4;
#pragma unroll
    for (int n = 0; n < 4; n++) {
        int col = col0 + wc + n * 16 + lr;
        float b = bias[col];
#pragma unroll
        for (int m = 0; m < 4; m++) {
#pragma unroll
            for (int j = 0; j < 4; j++) {
                int row = row0 + wr + m * 16 + rbase + j;
                if (row < M) out_bf[(size_t)row * Ncols + col] = f2bf(tanhf(acc[m][n][j] + b));
            }
        }
    }
#undef BIG_LOAD
#undef BIG_STORE
}

// ============ MFMA K=128 single-tile with full fused epilogue ============
template<bool ABF16, bool TANH, bool L2, bool RESID, bool AUX, bool AUXBF,
         bool F32OUT, bool BF16OUT, bool BIAS>
__global__ __launch_bounds__(256)
void mfma_ep(const void* __restrict__ A_, const unsigned short* __restrict__ Wt,
             const float* __restrict__ bias, const unsigned short* __restrict__ resid_bf,
             const void* __restrict__ aux_in, float* __restrict__ aux_out,
             float* __restrict__ out, unsigned short* __restrict__ out_bf, int M)
{
    __shared__ __align__(16) unsigned short Al[128][136];   // 34.8 KB

    const int tid  = threadIdx.x;
    const int row0 = blockIdx.x * 128;
    const int wv   = tid >> 6, lane = tid & 63;
    const int lr   = lane & 15;
    const int lk8  = (lane >> 4) * 8;
    const int wr   = wv * 32;

    if (ABF16) {
        const unsigned short* Ab = (const unsigned short*)A_;
#pragma unroll
        for (int i = 0; i < 8; i++) {
            int f = i * 256 + tid;
            int r = f >> 4, k8 = (f & 15) << 3;
            bf16x8 v = {0,0,0,0,0,0,0,0};
            if (row0 + r < M) v = *(const bf16x8*)(Ab + ((size_t)(row0 + r) << 7) + k8);
            *(bf16x8*)&Al[r][k8] = v;
        }
    } else {
        const float* Af = (const float*)A_;
#pragma unroll
        for (int i = 0; i < 16; i++) {
            int f = i * 256 + tid;
            int r = f >> 5, c4 = (f & 31) << 2;
            float4 a = make_float4(0.f, 0.f, 0.f, 0.f);
            if (row0 + r < M) a = *(const float4*)(Af + ((size_t)(row0 + r) << 7) + c4);
            *(ushort4*)&Al[r][c4] = make_ushort4(f2bf(a.x), f2bf(a.y), f2bf(a.z), f2bf(a.w));
        }
    }
    __syncthreads();

    f32x4 acc[2][8];
#pragma unroll
    for (int m = 0; m < 2; m++)
#pragma unroll
        for (int n = 0; n < 8; n++)
#pragma unroll
            for (int j = 0; j < 4; j++) acc[m][n][j] = 0.f;

#pragma unroll 1
    for (int ks = 0; ks < 4; ks++) {
        bf16x8 af[2], bn[8];
#pragma unroll
        for (int m = 0; m < 2; m++) af[m] = *(const bf16x8*)&Al[wr + m * 16 + lr][ks * 32 + lk8];
#pragma unroll
        for (int n = 0; n < 8; n++)
            bn[n] = *(const bf16x8*)(Wt + (((size_t)(n * 16 + lr)) << 7) + ks * 32 + lk8);
#pragma unroll
        for (int m = 0; m < 2; m++)
#pragma unroll
            for (int n = 0; n < 8; n++)
                acc[m][n] = __builtin_amdgcn_mfma_f32_16x16x32_bf16(af[m], bn[n], acc[m][n], 0, 0, 0);
    }

    const int rbase = (lane >> 4) * 4;
    float bv[8];
#pragma unroll
    for (int n = 0; n < 8; n++) bv[n] = BIAS ? bias[n * 16 + lr] : 0.f;

#pragma unroll
    for (int m = 0; m < 2; m++) {
#pragma unroll
        for (int j = 0; j < 4; j++) {
            int row = row0 + wr + m * 16 + rbase + j;
            bool ok = row < M;
            float v[8];
#pragma unroll
            for (int n = 0; n < 8; n++) {
                v[n] = acc[m][n][j] + bv[n];
                if (TANH) v[n] = tanhf(v[n]);
            }
            if (RESID) {
#pragma unroll
                for (int n = 0; n < 8; n++)
                    if (ok) v[n] += bf2f(resid_bf[((size_t)row << 7) + n * 16 + lr]);
            }
            if (L2) {
                float s = 0.f;
#pragma unroll
                for (int n = 0; n < 8; n++) s += v[n] * v[n];
#pragma unroll
                for (int msk = 8; msk >= 1; msk >>= 1) s += __shfl_xor(s, msk);
                float sc = 1.f / fmaxf(sqrtf(s), 1e-12f);
#pragma unroll
                for (int n = 0; n < 8; n++) v[n] *= sc;
            }
            if (ok) {
#pragma unroll
                for (int n = 0; n < 8; n++) {
                    size_t off = ((size_t)row << 7) + n * 16 + lr;
                    if (F32OUT)  out[off] = v[n];
                    if (BF16OUT) out_bf[off] = f2bf(v[n]);
                    if (AUX) {
                        float ai = AUXBF ? bf2f(((const unsigned short*)aux_in)[off])
                                         : ((const float*)aux_in)[off];
                        aux_out[off] = ai + v[n];
                    }
                }
            }
        }
    }
}

// ============ exact CSR build: hist + scan ============
__global__ __launch_bounds__(256)
void hist_k(const int* __restrict__ rows, int* __restrict__ cnt, int E)
{
    int e = blockIdx.x * 256 + threadIdx.x;
    if (e < E) atomicAdd(&cnt[rows[e]], 1);
}

#define SCAN_TILE 2048

__global__ __launch_bounds__(256)
void scan_phaseA(const int* __restrict__ cnt, int* __restrict__ tilesum, int N)
{
    __shared__ int sdata[256];
    int base = blockIdx.x * SCAN_TILE + threadIdx.x * 8;
    int s = 0;
#pragma unroll
    for (int j = 0; j < 8; j++) { int i = base + j; if (i < N) s += cnt[i]; }
    sdata[threadIdx.x] = s; __syncthreads();
    for (int off = 128; off > 0; off >>= 1) {
        if (threadIdx.x < off) sdata[threadIdx.x] += sdata[threadIdx.x + off];
        __syncthreads();
    }
    if (threadIdx.x == 0) tilesum[blockIdx.x] = sdata[0];
}

__global__ void scan_phaseB(int* __restrict__ tilesum, int* __restrict__ rowptr,
                            int numTiles, int N)
{
    if (threadIdx.x == 0 && blockIdx.x == 0) {
        int run = 0;
        for (int t = 0; t < numTiles; t++) { int v = tilesum[t]; tilesum[t] = run; run += v; }
        rowptr[N] = run;
    }
}

__global__ __launch_bounds__(256)
void scan_phaseC(const int* __restrict__ cnt, const int* __restrict__ tilesum,
                 int* __restrict__ rowptr, int N)
{
    __shared__ int sdata[256];
    int base = blockIdx.x * SCAN_TILE + threadIdx.x * 8;
    int loc[8]; int s = 0;
#pragma unroll
    for (int j = 0; j < 8; j++) {
        int i = base + j; int v = (i < N) ? cnt[i] : 0;
        loc[j] = s; s += v;
    }
    sdata[threadIdx.x] = s; __syncthreads();
    int x = s;
    for (int off = 1; off < 256; off <<= 1) {
        int t = 0;
        if (threadIdx.x >= off) t = sdata[threadIdx.x - off];
        __syncthreads();
        x += t;
        sdata[threadIdx.x] = x;
        __syncthreads();
    }
    int texcl = x - s + tilesum[blockIdx.x];
#pragma unroll
    for (int j = 0; j < 8; j++) {
        int i = base + j;
        if (i < N) rowptr[i] = texcl + loc[j];
    }
}

// ============ bucketed reorder (kills scatter line-amplification) ============
#define RCHUNK 16384

__global__ __launch_bounds__(256)
void bhist_k(const int* __restrict__ rows, int* __restrict__ bcnt, int E, int NB)
{
    __shared__ int lc[1024];
    for (int b = threadIdx.x; b < NB; b += 256) lc[b] = 0;
    __syncthreads();
    int start = blockIdx.x * RCHUNK;
    int end = min(start + RCHUNK, E);
    for (int i = start + threadIdx.x; i < end; i += 256)
        atomicAdd(&lc[rows[i] >> 7], 1);
    __syncthreads();
    for (int b = threadIdx.x; b < NB; b += 256)
        if (lc[b]) atomicAdd(&bcnt[b], lc[b]);
}

__global__ void init_bcur(const int* __restrict__ bbase, int* __restrict__ bcur, int NB)
{
    int b = blockIdx.x * 256 + threadIdx.x;
    if (b < NB) bcur[b] = bbase[b];
}

// group edges by 128-row bucket; coalesced run-reserved writes; row_low packed in col bits 17..23
__global__ __launch_bounds__(256)
void bucket_scatter(const int* __restrict__ rows, const int* __restrict__ cols,
                    const float* __restrict__ vals, int* __restrict__ bcur,
                    int2* __restrict__ tmp, int E, int NB)
{
    __shared__ int lcnt[1024];
    __shared__ int lbase[1024];
    for (int b = threadIdx.x; b < NB; b += 256) lcnt[b] = 0;
    __syncthreads();
    int start = blockIdx.x * RCHUNK;
    int end = min(start + RCHUNK, E);
    for (int i = start + threadIdx.x; i < end; i += 256)
        atomicAdd(&lcnt[rows[i] >> 7], 1);
    __syncthreads();
    for (int b = threadIdx.x; b < NB; b += 256) {
        int c = lcnt[b];
        lbase[b] = c ? atomicAdd(&bcur[b], c) : 0;
        lcnt[b] = 0;
    }
    __syncthreads();
    for (int i = start + threadIdx.x; i < end; i += 256) {
        int r = rows[i];
        int b = r >> 7;
        int off = atomicAdd(&lcnt[b], 1);
        tmp[lbase[b] + off] = make_int2(cols[i] | ((r & 127) << 17), __float_as_int(vals[i]));
    }
}

// one block per bucket: scatter to final CSR positions inside an L2-resident 32KB window
__global__ __launch_bounds__(256)
void csr_place(const int2* __restrict__ tmp, const int* __restrict__ bbase,
               const int* __restrict__ rowptr, int* __restrict__ cur,
               int2* __restrict__ packed)
{
    int b = blockIdx.x;
    int s = bbase[b], e = bbase[b + 1];
    int rb = b << 7;
    for (int i = s + threadIdx.x; i < e; i += 256) {
        int2 t = tmp[i];
        int r = rb + (((unsigned)t.x) >> 17);
        int c = t.x & 0x1FFFF;
        int pos = rowptr[r] + atomicAdd(&cur[r], 1);
        packed[pos] = make_int2(c, t.y);
    }
}

// ============ CSR SpMM: bf16 gathers, bf16 output, wave per row ============
__global__ __launch_bounds__(256)
void spmm_csr(const int* __restrict__ rowptr, const int2* __restrict__ packed,
              const unsigned short* __restrict__ embb, unsigned short* __restrict__ hb, int N)
{
    const int wv = threadIdx.x >> 6, lane = threadIdx.x & 63;
    const int r = blockIdx.x * 4 + wv;
    if (r >= N) return;
    const int s = rowptr[r], e = rowptr[r + 1];
    const int l2 = lane * 2;

    float ax0=0.f,ay0=0.f,ax1=0.f,ay1=0.f,ax2=0.f,ay2=0.f,ax3=0.f,ay3=0.f;
    int i = s;
    for (; i + 8 <= e; i += 8) {
        int2 p0=packed[i+0],p1=packed[i+1],p2=packed[i+2],p3=packed[i+3];
        int2 p4=packed[i+4],p5=packed[i+5],p6=packed[i+6],p7=packed[i+7];
        unsigned m0 = *(const unsigned*)(embb + ((size_t)p0.x << 7) + l2);
        unsigned m1 = *(const unsigned*)(embb + ((size_t)p1.x << 7) + l2);
        unsigned m2 = *(const unsigned*)(embb + ((size_t)p2.x << 7) + l2);
        unsigned m3 = *(const unsigned*)(embb + ((size_t)p3.x << 7) + l2);
        unsigned m4 = *(const unsigned*)(embb + ((size_t)p4.x << 7) + l2);
        unsigned m5 = *(const unsigned*)(embb + ((size_t)p5.x << 7) + l2);
        unsigned m6 = *(const unsigned*)(embb + ((size_t)p6.x << 7) + l2);
        unsigned m7 = *(const unsigned*)(embb + ((size_t)p7.x << 7) + l2);
        float v0=__int_as_float(p0.y), v1=__int_as_float(p1.y);
        float v2=__int_as_float(p2.y), v3=__int_as_float(p3.y);
        float v4=__int_as_float(p4.y), v5=__int_as_float(p5.y);
        float v6=__int_as_float(p6.y), v7=__int_as_float(p7.y);
        ax0 += v0*__uint_as_float(m0<<16); ay0 += v0*__uint_as_float(m0&0xffff0000u);
        ax1 += v1*__uint_as_float(m1<<16); ay1 += v1*__uint_as_float(m1&0xffff0000u);
        ax2 += v2*__uint_as_float(m2<<16); ay2 += v2*__uint_as_float(m2&0xffff0000u);
        ax3 += v3*__uint_as_float(m3<<16); ay3 += v3*__uint_as_float(m3&0xffff0000u);
        ax0 += v4*__uint_as_float(m4<<16); ay0 += v4*__uint_as_float(m4&0xffff0000u);
        ax1 += v5*__uint_as_float(m5<<16); ay1 += v5*__uint_as_float(m5&0xffff0000u);
        ax2 += v6*__uint_as_float(m6<<16); ay2 += v6*__uint_as_float(m6&0xffff0000u);
        ax3 += v7*__uint_as_float(m7<<16); ay3 += v7*__uint_as_float(m7&0xffff0000u);
    }
    for (; i < e; i++) {
        int2 p = packed[i];
        unsigned m = *(const unsigned*)(embb + ((size_t)p.x << 7) + l2);
        float v = __int_as_float(p.y);
        ax0 += v*__uint_as_float(m<<16); ay0 += v*__uint_as_float(m&0xffff0000u);
    }
    float sx = (ax0+ax1)+(ax2+ax3);
    float sy = (ay0+ay1)+(ay2+ay3);
    unsigned o = (unsigned)f2bf(sx) | ((unsigned)f2bf(sy) << 16);
    *(unsigned*)(hb + ((size_t)r << 7) + l2) = o;
}

// ============ launch ============
extern "C" void kernel_launch(void* const* d_in, const int* in_sizes, int n_in,
                              void* d_out, int out_size, void* d_ws, size_t ws_size,
                              hipStream_t stream)
{
    const float* feat  = (const float*)d_in[0];
    const int*   srows = (const int*)  d_in[1];
    const int*   scols = (const int*)  d_in[2];
    const float* svals = (const float*)d_in[3];
    const float* Wf0   = (const float*)d_in[4];
    const float* bf0   = (const float*)d_in[5];
    const float* Wf1   = (const float*)d_in[6];
    const float* bf1   = (const float*)d_in[7];
    const float* Wg    = (const float*)d_in[8];
    const float* Wemb  = (const float*)d_in[9];
    const float* bemb  = (const float*)d_in[10];
    const float* Wl    = (const float*)d_in[11];
    const float* bl    = (const float*)d_in[12];
    const float* Wr    = (const float*)d_in[13];
    const float* br    = (const float*)d_in[14];

    const int M = in_sizes[0] / 512;   // 100000 nodes
    const int E = in_sizes[1];         // 3200000 edges
    const int NB = (M + 127) >> 7;     // 782 buckets

    float* out = (float*)d_out;
    float* R0 = out;                        // emb final
    float* R1 = out + (size_t)M * 128;      // lft final
    float* R2 = out + (size_t)M * 256;      // rgt final

    // ---- ws layout (~78.2 MB) ----
    float* ws = (float*)d_ws;
    float* accf = ws;                                      // [M,128] f32 gnn_acc; tmp aliases it
    int2*  tmp  = (int2*)ws;                               // [E] int2 (25.6MB <= 51.2MB, dead before s4)
    int*   ip = (int*)(ws + (size_t)M * 128);
    int*   rowptr  = ip;                                   // M+1
    int*   cnt     = ip + (((size_t)M + 4) & ~(size_t)3);  // M (hist + cur)
    int2*  packed  = (int2*)(cnt + M);                     // E
    int*   tilesum = (int*)(packed + E);                   // 64
    int*   bcnt    = tilesum + 64;                         // NB
    int*   bbase   = bcnt + 1024;                          // NB+1
    int*   bcur    = bbase + 1032;                         // NB
    unsigned short* Wt0   = (unsigned short*)(bcur + 1024);    // [256][512]
    unsigned short* Wt1   = Wt0 + 256 * 512;                   // [128][256]
    unsigned short* Wg0t  = Wt1 + 128 * 256;                   // 7x [128][128]
    unsigned short* Wg1t  = Wg0t + 16384;
    unsigned short* Wembt = Wg1t + 16384;
    unsigned short* Wl0t  = Wembt + 16384;
    unsigned short* Wl1t  = Wl0t + 16384;
    unsigned short* Wr0t  = Wl1t + 16384;
    unsigned short* Wr1t  = Wr0t + 16384;

    // ---- d_out scratch halves (R0a=R0 1st 25.6MB, R0b=2nd, etc.) ----
    unsigned short* R0a = (unsigned short*)R0;
    unsigned short* R0b = (unsigned short*)R0 + (size_t)M * 128;
    unsigned short* R1a = (unsigned short*)R1;
    unsigned short* x1_bf   = (unsigned short*)R2;  // [M,256], dead after s2
    unsigned short* x_bf    = R0a;                  // s2 -> s4(aux) ; spmm3 gather src
    unsigned short* h_bf    = R0b;                  // spmm3->s4 ; spmm5->s6
    unsigned short* n0_bf   = R1a;                  // s4 -> spmm5
    unsigned short* n1_bf   = R0a;                  // s6 -> s10/s8 (x_bf dead)
    unsigned short* rgt0_bf = R1a;                  // s10 -> s11 (n0 dead)
    unsigned short* lft0_bf = R0b;                  // s8 -> s9 (h dead)

    dim3 blk(256);
    const int gm128 = (M + 127) / 128;
    const int ge    = (E + 255) / 256;
    const int nch   = (E + RCHUNK - 1) / RCHUNK;
    const int numTiles = (M + SCAN_TILE - 1) / SCAN_TILE;

    // weight converts
    wconv<<<(512*256 + 255)/256, blk, 0, stream>>>(Wf0, Wt0, 512, 256);
    wconv<<<(256*128 + 255)/256, blk, 0, stream>>>(Wf1, Wt1, 256, 128);
    wconv<<<64, blk, 0, stream>>>(Wg,          Wg0t,  128, 128);
    wconv<<<64, blk, 0, stream>>>(Wg + 16384,  Wg1t,  128, 128);
    wconv<<<64, blk, 0, stream>>>(Wemb,        Wembt, 128, 128);
    wconv<<<64, blk, 0, stream>>>(Wl,          Wl0t,  128, 128);
    wconv<<<64, blk, 0, stream>>>(Wl + 16384,  Wl1t,  128, 128);
    wconv<<<64, blk, 0, stream>>>(Wr,          Wr0t,  128, 128);
    wconv<<<64, blk, 0, stream>>>(Wr + 16384,  Wr1t,  128, 128);

    // ---- CSR build: bucket pass ----
    hipMemsetAsync(bcnt, 0, (size_t)NB * 4, stream);
    bhist_k<<<nch, blk, 0, stream>>>(srows, bcnt, E, NB);
    scan_phaseA<<<1, blk, 0, stream>>>(bcnt, tilesum, NB);
    scan_phaseB<<<1, 64, 0, stream>>>(tilesum, bbase, 1, NB);
    scan_phaseC<<<1, blk, 0, stream>>>(bcnt, tilesum, bbase, NB);
    init_bcur<<<(NB + 255)/256, blk, 0, stream>>>(bbase, bcur, NB);
    bucket_scatter<<<nch, blk, 0, stream>>>(srows, scols, svals, bcur, tmp, E, NB);
    // ---- exact rowptr ----
    hipMemsetAsync(cnt, 0, (size_t)M * 4, stream);
    hist_k<<<ge, blk, 0, stream>>>(srows, cnt, E);
    scan_phaseA<<<numTiles, blk, 0, stream>>>(cnt, tilesum, M);
    scan_phaseB<<<1, 64, 0, stream>>>(tilesum, rowptr, numTiles, M);
    scan_phaseC<<<numTiles, blk, 0, stream>>>(cnt, tilesum, rowptr, M);
    hipMemsetAsync(cnt, 0, (size_t)M * 4, stream);
    // ---- final place (L2-window scatter) ----
    csr_place<<<NB, blk, 0, stream>>>(tmp, bbase, rowptr, cnt, packed);

    // ---- network ----
    // s1: x1_bf = tanh(feat @ Wf0 + bf0)   [f32 A fused-convert]
    mfma_big<false><<<dim3(gm128,2),blk,0,stream>>>(feat, Wt0, bf0, x1_bf, M, 512, 256);
    // s2: x_bf = tanh(x1 @ Wf1 + bf1)
    mfma_big<true><<<dim3(gm128,1),blk,0,stream>>>(x1_bf, Wt1, bf1, x_bf, M, 256, 128);
    // spmm3: h_bf = S @ x
    spmm_csr<<<(M + 3) / 4, blk, 0, stream>>>(rowptr, packed, x_bf, h_bf, M);
    // s4: n0 = l2norm(tanh(h @ Wg0)) -> n0_bf; accf = x + n0
    mfma_ep<true,true,true,false,true,true,false,true,false><<<gm128,blk,0,stream>>>(
        h_bf, Wg0t, nullptr, nullptr, x_bf, accf, nullptr, n0_bf, M);
    // spmm5: h_bf = S @ n0
    spmm_csr<<<(M + 3) / 4, blk, 0, stream>>>(rowptr, packed, n0_bf, h_bf, M);
    // s6: n1 = l2norm(tanh(h @ Wg1)) -> n1_bf; accf += n1 (in-place)
    mfma_ep<true,true,true,false,true,false,false,true,false><<<gm128,blk,0,stream>>>(
        h_bf, Wg1t, nullptr, nullptr, accf, accf, nullptr, n1_bf, M);
    // s10: rgt0 = tanh(n1 @ Wr0 + br0) + n1 -> rgt0_bf
    mfma_ep<true,true,false,true,false,false,false,true,true><<<gm128,blk,0,stream>>>(
        n1_bf, Wr0t, br, n1_bf, nullptr, nullptr, nullptr, rgt0_bf, M);
    // s11: rgt = tanh(rgt0 @ Wr1 + br1) -> R2 final
    mfma_ep<true,true,false,false,false,false,true,false,true><<<gm128,blk,0,stream>>>(
        rgt0_bf, Wr1t, br + 128, nullptr, nullptr, nullptr, R2, nullptr, M);
    // s8: lft0 = tanh(n1 @ Wl0 + bl0) + n1 -> lft0_bf
    mfma_ep<true,true,false,true,false,false,false,true,true><<<gm128,blk,0,stream>>>(
        n1_bf, Wl0t, bl, n1_bf, nullptr, nullptr, nullptr, lft0_bf, M);
    // s9: lft = tanh(lft0 @ Wl1 + bl1) -> R1 final
    mfma_ep<true,true,false,false,false,false,true,false,true><<<gm128,blk,0,stream>>>(
        lft0_bf, Wl1t, bl + 128, nullptr, nullptr, nullptr, R1, nullptr, M);
    // s7: emb = l2norm(accf @ Wemb + bemb) -> R0 final (last: frees R0 scratch)
    mfma_ep<false,false,true,false,false,false,true,false,true><<<gm128,blk,0,stream>>>(
        accf, Wembt, bemb, nullptr, nullptr, nullptr, R0, nullptr, M);
}

// Round 8
// 952.980 us; speedup vs baseline: 1.2631x; 1.2631x over previous
//
#include <hip/hip_runtime.h>
#include <math.h>

typedef short bf16x8 __attribute__((ext_vector_type(8)));
typedef float f32x4  __attribute__((ext_vector_type(4)));

__device__ __forceinline__ unsigned short f2bf(float x) {
    unsigned u = __float_as_uint(x);
    unsigned r = u + 0x7FFFu + ((u >> 16) & 1u);   // RNE
    return (unsigned short)(r >> 16);
}
__device__ __forceinline__ float bf2f(unsigned short b) {
    return __uint_as_float(((unsigned)b) << 16);
}

// ============ weight convert+transpose: Wt[n][k] = bf16(W[k][n]) ============
__global__ __launch_bounds__(256)
void wconv(const float* __restrict__ W, unsigned short* __restrict__ Wt, int K, int N)
{
    int id = blockIdx.x * 256 + threadIdx.x;
    if (id >= K * N) return;
    int n = id / K, k = id - n * K;
    Wt[(size_t)n * K + k] = f2bf(W[(size_t)k * N + n]);
}

// ============ bulk f32 -> bf16 (for feat; streams at HBM BW) ============
__global__ __launch_bounds__(256)
void f32_to_bf16(const float* __restrict__ in, unsigned short* __restrict__ outb, long n8)
{
    long id = (long)blockIdx.x * 256 + threadIdx.x;   // one per 8 elems
    if (id >= n8) return;
    const float4* p = (const float4*)(in + id * 8);
    float4 a = p[0], b = p[1];
    *(ushort4*)(outb + id * 8)     = make_ushort4(f2bf(a.x), f2bf(a.y), f2bf(a.z), f2bf(a.w));
    *(ushort4*)(outb + id * 8 + 4) = make_ushort4(f2bf(b.x), f2bf(b.y), f2bf(b.z), f2bf(b.w));
}

// ============ MFMA GEMM (R6-proven): bf16 A, single-buffer LDS, B from global ============
// A bf16 [M,K]; Wt bf16 [Ncols][K]. Tile 128x128, 4 waves 2x2, BK=64.
// out: bf16 tanh(A@W + bias).
__global__ __launch_bounds__(256)
void mfma_big(const unsigned short* __restrict__ Ab, const unsigned short* __restrict__ Wt,
              const float* __restrict__ bias, unsigned short* __restrict__ out_bf,
              int M, int K, int Ncols)
{
    __shared__ __align__(16) unsigned short Al[128][72];   // 18.4 KB

    const int tid  = threadIdx.x;
    const int row0 = blockIdx.x * 128;
    const int col0 = blockIdx.y * 128;
    const int wv   = tid >> 6, lane = tid & 63;
    const int wr   = (wv >> 1) * 64, wc = (wv & 1) * 64;
    const int lr   = lane & 15;
    const int lk8  = (lane >> 4) * 8;

    f32x4 acc[4][4];
#pragma unroll
    for (int m = 0; m < 4; m++)
#pragma unroll
        for (int n = 0; n < 4; n++)
#pragma unroll
            for (int j = 0; j < 4; j++) acc[m][n][j] = 0.f;

    for (int k0 = 0; k0 < K; k0 += 64) {
#pragma unroll
        for (int i = 0; i < 4; i++) {
            int f = i * 256 + tid;
            int r = f >> 3, k8 = (f & 7) << 3;
            bf16x8 v = {0,0,0,0,0,0,0,0};
            if (row0 + r < M) v = *(const bf16x8*)(Ab + (size_t)(row0 + r) * K + k0 + k8);
            *(bf16x8*)&Al[r][k8] = v;
        }
        __syncthreads();
#pragma unroll
        for (int kk = 0; kk < 64; kk += 32) {
            bf16x8 af[4], bfr[4];
#pragma unroll
            for (int m = 0; m < 4; m++) af[m] = *(const bf16x8*)&Al[wr + m * 16 + lr][kk + lk8];
#pragma unroll
            for (int n = 0; n < 4; n++)
                bfr[n] = *(const bf16x8*)(Wt + (size_t)(col0 + wc + n * 16 + lr) * K + k0 + kk + lk8);
#pragma unroll
            for (int m = 0; m < 4; m++)
#pragma unroll
                for (int n = 0; n < 4; n++)
                    acc[m][n] = __builtin_amdgcn_mfma_f32_16x16x32_bf16(af[m], bfr[n], acc[m][n], 0, 0, 0);
        }
        __syncthreads();
    }

    const int rbase = (lane >> 4) * 4;
#pragma unroll
    for (int n = 0; n < 4; n++) {
        int col = col0 + wc + n * 16 + lr;
        float b = bias[col];
#pragma unroll
        for (int m = 0; m < 4; m++) {
#pragma unroll
            for (int j = 0; j < 4; j++) {
                int row = row0 + wr + m * 16 + rbase + j;
                if (row < M) out_bf[(size_t)row * Ncols + col] = f2bf(tanhf(acc[m][n][j] + b));
            }
        }
    }
}

// ============ MFMA K=128 single-tile with full fused epilogue ============
template<bool ABF16, bool TANH, bool L2, bool RESID, bool AUX, bool AUXBF,
         bool F32OUT, bool BF16OUT, bool BIAS>
__global__ __launch_bounds__(256)
void mfma_ep(const void* __restrict__ A_, const unsigned short* __restrict__ Wt,
             const float* __restrict__ bias, const unsigned short* __restrict__ resid_bf,
             const void* __restrict__ aux_in, float* __restrict__ aux_out,
             float* __restrict__ out, unsigned short* __restrict__ out_bf, int M)
{
    __shared__ __align__(16) unsigned short Al[128][136];   // 34.8 KB

    const int tid  = threadIdx.x;
    const int row0 = blockIdx.x * 128;
    const int wv   = tid >> 6, lane = tid & 63;
    const int lr   = lane & 15;
    const int lk8  = (lane >> 4) * 8;
    const int wr   = wv * 32;

    if (ABF16) {
        const unsigned short* Ab = (const unsigned short*)A_;
#pragma unroll
        for (int i = 0; i < 8; i++) {
            int f = i * 256 + tid;
            int r = f >> 4, k8 = (f & 15) << 3;
            bf16x8 v = {0,0,0,0,0,0,0,0};
            if (row0 + r < M) v = *(const bf16x8*)(Ab + ((size_t)(row0 + r) << 7) + k8);
            *(bf16x8*)&Al[r][k8] = v;
        }
    } else {
        const float* Af = (const float*)A_;
#pragma unroll
        for (int i = 0; i < 16; i++) {
            int f = i * 256 + tid;
            int r = f >> 5, c4 = (f & 31) << 2;
            float4 a = make_float4(0.f, 0.f, 0.f, 0.f);
            if (row0 + r < M) a = *(const float4*)(Af + ((size_t)(row0 + r) << 7) + c4);
            *(ushort4*)&Al[r][c4] = make_ushort4(f2bf(a.x), f2bf(a.y), f2bf(a.z), f2bf(a.w));
        }
    }
    __syncthreads();

    f32x4 acc[2][8];
#pragma unroll
    for (int m = 0; m < 2; m++)
#pragma unroll
        for (int n = 0; n < 8; n++)
#pragma unroll
            for (int j = 0; j < 4; j++) acc[m][n][j] = 0.f;

#pragma unroll 1
    for (int ks = 0; ks < 4; ks++) {
        bf16x8 af[2], bn[8];
#pragma unroll
        for (int m = 0; m < 2; m++) af[m] = *(const bf16x8*)&Al[wr + m * 16 + lr][ks * 32 + lk8];
#pragma unroll
        for (int n = 0; n < 8; n++)
            bn[n] = *(const bf16x8*)(Wt + (((size_t)(n * 16 + lr)) << 7) + ks * 32 + lk8);
#pragma unroll
        for (int m = 0; m < 2; m++)
#pragma unroll
            for (int n = 0; n < 8; n++)
                acc[m][n] = __builtin_amdgcn_mfma_f32_16x16x32_bf16(af[m], bn[n], acc[m][n], 0, 0, 0);
    }

    const int rbase = (lane >> 4) * 4;
    float bv[8];
#pragma unroll
    for (int n = 0; n < 8; n++) bv[n] = BIAS ? bias[n * 16 + lr] : 0.f;

#pragma unroll
    for (int m = 0; m < 2; m++) {
#pragma unroll
        for (int j = 0; j < 4; j++) {
            int row = row0 + wr + m * 16 + rbase + j;
            bool ok = row < M;
            float v[8];
#pragma unroll
            for (int n = 0; n < 8; n++) {
                v[n] = acc[m][n][j] + bv[n];
                if (TANH) v[n] = tanhf(v[n]);
            }
            if (RESID) {
#pragma unroll
                for (int n = 0; n < 8; n++)
                    if (ok) v[n] += bf2f(resid_bf[((size_t)row << 7) + n * 16 + lr]);
            }
            if (L2) {
                float s = 0.f;
#pragma unroll
                for (int n = 0; n < 8; n++) s += v[n] * v[n];
#pragma unroll
                for (int msk = 8; msk >= 1; msk >>= 1) s += __shfl_xor(s, msk);
                float sc = 1.f / fmaxf(sqrtf(s), 1e-12f);
#pragma unroll
                for (int n = 0; n < 8; n++) v[n] *= sc;
            }
            if (ok) {
#pragma unroll
                for (int n = 0; n < 8; n++) {
                    size_t off = ((size_t)row << 7) + n * 16 + lr;
                    if (F32OUT)  out[off] = v[n];
                    if (BF16OUT) out_bf[off] = f2bf(v[n]);
                    if (AUX) {
                        float ai = AUXBF ? bf2f(((const unsigned short*)aux_in)[off])
                                         : ((const float*)aux_in)[off];
                        aux_out[off] = ai + v[n];
                    }
                }
            }
        }
    }
}

// ============ scan helpers (bucket-level only, NB<=2048) ============
#define SCAN_TILE 2048

__global__ __launch_bounds__(256)
void scan_phaseA(const int* __restrict__ cnt, int* __restrict__ tilesum, int N)
{
    __shared__ int sdata[256];
    int base = blockIdx.x * SCAN_TILE + threadIdx.x * 8;
    int s = 0;
#pragma unroll
    for (int j = 0; j < 8; j++) { int i = base + j; if (i < N) s += cnt[i]; }
    sdata[threadIdx.x] = s; __syncthreads();
    for (int off = 128; off > 0; off >>= 1) {
        if (threadIdx.x < off) sdata[threadIdx.x] += sdata[threadIdx.x + off];
        __syncthreads();
    }
    if (threadIdx.x == 0) tilesum[blockIdx.x] = sdata[0];
}

__global__ void scan_phaseB(int* __restrict__ tilesum, int* __restrict__ rowptr,
                            int numTiles, int N)
{
    if (threadIdx.x == 0 && blockIdx.x == 0) {
        int run = 0;
        for (int t = 0; t < numTiles; t++) { int v = tilesum[t]; tilesum[t] = run; run += v; }
        rowptr[N] = run;
    }
}

__global__ __launch_bounds__(256)
void scan_phaseC(const int* __restrict__ cnt, const int* __restrict__ tilesum,
                 int* __restrict__ rowptr, int N)
{
    __shared__ int sdata[256];
    int base = blockIdx.x * SCAN_TILE + threadIdx.x * 8;
    int loc[8]; int s = 0;
#pragma unroll
    for (int j = 0; j < 8; j++) {
        int i = base + j; int v = (i < N) ? cnt[i] : 0;
        loc[j] = s; s += v;
    }
    sdata[threadIdx.x] = s; __syncthreads();
    int x = s;
    for (int off = 1; off < 256; off <<= 1) {
        int t = 0;
        if (threadIdx.x >= off) t = sdata[threadIdx.x - off];
        __syncthreads();
        x += t;
        sdata[threadIdx.x] = x;
        __syncthreads();
    }
    int texcl = x - s + tilesum[blockIdx.x];
#pragma unroll
    for (int j = 0; j < 8; j++) {
        int i = base + j;
        if (i < N) rowptr[i] = texcl + loc[j];
    }
}

// ============ bucketed reorder (no line-thrashing scatter) ============
#define RCHUNK 16384

__global__ __launch_bounds__(256)
void bhist_k(const int* __restrict__ rows, int* __restrict__ bcnt, int E, int NB)
{
    __shared__ int lc[1024];
    for (int b = threadIdx.x; b < NB; b += 256) lc[b] = 0;
    __syncthreads();
    int start = blockIdx.x * RCHUNK;
    int end = min(start + RCHUNK, E);
    for (int i = start + threadIdx.x; i < end; i += 256)
        atomicAdd(&lc[rows[i] >> 7], 1);
    __syncthreads();
    for (int b = threadIdx.x; b < NB; b += 256)
        if (lc[b]) atomicAdd(&bcnt[b], lc[b]);
}

__global__ void init_bcur(const int* __restrict__ bbase, int* __restrict__ bcur, int NB)
{
    int b = blockIdx.x * 256 + threadIdx.x;
    if (b < NB) bcur[b] = bbase[b];
}

// group edges by 128-row bucket; run-reserved coalesced writes; row_low in col bits 17..23
__global__ __launch_bounds__(256)
void bucket_scatter(const int* __restrict__ rows, const int* __restrict__ cols,
                    const float* __restrict__ vals, int* __restrict__ bcur,
                    int2* __restrict__ tmp, int E, int NB)
{
    __shared__ int lcnt[1024];
    __shared__ int lbase[1024];
    for (int b = threadIdx.x; b < NB; b += 256) lcnt[b] = 0;
    __syncthreads();
    int start = blockIdx.x * RCHUNK;
    int end = min(start + RCHUNK, E);
    for (int i = start + threadIdx.x; i < end; i += 256)
        atomicAdd(&lcnt[rows[i] >> 7], 1);
    __syncthreads();
    for (int b = threadIdx.x; b < NB; b += 256) {
        int c = lcnt[b];
        lbase[b] = c ? atomicAdd(&bcur[b], c) : 0;
        lcnt[b] = 0;
    }
    __syncthreads();
    for (int i = start + threadIdx.x; i < end; i += 256) {
        int r = rows[i];
        int b = r >> 7;
        int off = atomicAdd(&lcnt[b], 1);
        tmp[lbase[b] + off] = make_int2(cols[i] | ((r & 127) << 17), __float_as_int(vals[i]));
    }
}

// one block per bucket: local row-count + scan -> writes rowptr AND places edges
__global__ __launch_bounds__(256)
void csr_place(const int2* __restrict__ tmp, const int* __restrict__ bbase,
               int* __restrict__ rowptr, int2* __restrict__ packed, int M, int NB)
{
    __shared__ int lcnt[128];
    __shared__ int lofs[128];
    const int tid = threadIdx.x;
    const int b = blockIdx.x;
    const int s = bbase[b], e = bbase[b + 1];
    const int rb = b << 7;
    if (tid < 128) lcnt[tid] = 0;
    __syncthreads();
    for (int i = s + tid; i < e; i += 256)
        atomicAdd(&lcnt[(((unsigned)tmp[i].x) >> 17) & 127], 1);
    __syncthreads();
    if (tid == 0) {
        int run = s;
#pragma unroll 8
        for (int r = 0; r < 128; r++) { lofs[r] = run; run += lcnt[r]; }
    }
    __syncthreads();
    if (tid < 128 && rb + tid < M) rowptr[rb + tid] = lofs[tid];
    if (b == NB - 1 && tid == 0) rowptr[M] = e;
    if (tid < 128) lcnt[tid] = 0;
    __syncthreads();
    for (int i = s + tid; i < e; i += 256) {
        int2 t = tmp[i];
        int rl = (((unsigned)t.x) >> 17) & 127;
        int pos = lofs[rl] + atomicAdd(&lcnt[rl], 1);
        packed[pos] = make_int2(t.x & 0x1FFFF, t.y);
    }
}

// ============ CSR SpMM: bf16 gathers, bf16 output, wave per row ============
__global__ __launch_bounds__(256)
void spmm_csr(const int* __restrict__ rowptr, const int2* __restrict__ packed,
              const unsigned short* __restrict__ embb, unsigned short* __restrict__ hb, int N)
{
    const int wv = threadIdx.x >> 6, lane = threadIdx.x & 63;
    const int r = blockIdx.x * 4 + wv;
    if (r >= N) return;
    const int s = rowptr[r], e = rowptr[r + 1];
    const int l2 = lane * 2;

    float ax0=0.f,ay0=0.f,ax1=0.f,ay1=0.f,ax2=0.f,ay2=0.f,ax3=0.f,ay3=0.f;
    int i = s;
    for (; i + 8 <= e; i += 8) {
        int2 p0=packed[i+0],p1=packed[i+1],p2=packed[i+2],p3=packed[i+3];
        int2 p4=packed[i+4],p5=packed[i+5],p6=packed[i+6],p7=packed[i+7];
        unsigned m0 = *(const unsigned*)(embb + ((size_t)p0.x << 7) + l2);
        unsigned m1 = *(const unsigned*)(embb + ((size_t)p1.x << 7) + l2);
        unsigned m2 = *(const unsigned*)(embb + ((size_t)p2.x << 7) + l2);
        unsigned m3 = *(const unsigned*)(embb + ((size_t)p3.x << 7) + l2);
        unsigned m4 = *(const unsigned*)(embb + ((size_t)p4.x << 7) + l2);
        unsigned m5 = *(const unsigned*)(embb + ((size_t)p5.x << 7) + l2);
        unsigned m6 = *(const unsigned*)(embb + ((size_t)p6.x << 7) + l2);
        unsigned m7 = *(const unsigned*)(embb + ((size_t)p7.x << 7) + l2);
        float v0=__int_as_float(p0.y), v1=__int_as_float(p1.y);
        float v2=__int_as_float(p2.y), v3=__int_as_float(p3.y);
        float v4=__int_as_float(p4.y), v5=__int_as_float(p5.y);
        float v6=__int_as_float(p6.y), v7=__int_as_float(p7.y);
        ax0 += v0*__uint_as_float(m0<<16); ay0 += v0*__uint_as_float(m0&0xffff0000u);
        ax1 += v1*__uint_as_float(m1<<16); ay1 += v1*__uint_as_float(m1&0xffff0000u);
        ax2 += v2*__uint_as_float(m2<<16); ay2 += v2*__uint_as_float(m2&0xffff0000u);
        ax3 += v3*__uint_as_float(m3<<16); ay3 += v3*__uint_as_float(m3&0xffff0000u);
        ax0 += v4*__uint_as_float(m4<<16); ay0 += v4*__uint_as_float(m4&0xffff0000u);
        ax1 += v5*__uint_as_float(m5<<16); ay1 += v5*__uint_as_float(m5&0xffff0000u);
        ax2 += v6*__uint_as_float(m6<<16); ay2 += v6*__uint_as_float(m6&0xffff0000u);
        ax3 += v7*__uint_as_float(m7<<16); ay3 += v7*__uint_as_float(m7&0xffff0000u);
    }
    for (; i < e; i++) {
        int2 p = packed[i];
        unsigned m = *(const unsigned*)(embb + ((size_t)p.x << 7) + l2);
        float v = __int_as_float(p.y);
        ax0 += v*__uint_as_float(m<<16); ay0 += v*__uint_as_float(m&0xffff0000u);
    }
    float sx = (ax0+ax1)+(ax2+ax3);
    float sy = (ay0+ay1)+(ay2+ay3);
    unsigned o = (unsigned)f2bf(sx) | ((unsigned)f2bf(sy) << 16);
    *(unsigned*)(hb + ((size_t)r << 7) + l2) = o;
}

// ============ launch ============
extern "C" void kernel_launch(void* const* d_in, const int* in_sizes, int n_in,
                              void* d_out, int out_size, void* d_ws, size_t ws_size,
                              hipStream_t stream)
{
    const float* feat  = (const float*)d_in[0];
    const int*   srows = (const int*)  d_in[1];
    const int*   scols = (const int*)  d_in[2];
    const float* svals = (const float*)d_in[3];
    const float* Wf0   = (const float*)d_in[4];
    const float* bf0   = (const float*)d_in[5];
    const float* Wf1   = (const float*)d_in[6];
    const float* bf1   = (const float*)d_in[7];
    const float* Wg    = (const float*)d_in[8];
    const float* Wemb  = (const float*)d_in[9];
    const float* bemb  = (const float*)d_in[10];
    const float* Wl    = (const float*)d_in[11];
    const float* bl    = (const float*)d_in[12];
    const float* Wr    = (const float*)d_in[13];
    const float* br    = (const float*)d_in[14];

    const int M = in_sizes[0] / 512;   // 100000 nodes
    const int E = in_sizes[1];         // 3200000 edges
    const int NB = (M + 127) >> 7;     // 782 buckets

    float* out = (float*)d_out;
    float* R0 = out;                        // emb final
    float* R1 = out + (size_t)M * 128;      // lft final
    float* R2 = out + (size_t)M * 256;      // rgt final

    // ---- ws layout ----
    float* ws = (float*)d_ws;
    float* accf = ws;                                      // [M,128] f32 gnn_acc; tmp aliases
    int2*  tmp  = (int2*)ws;                               // [E] int2, dead before s4
    int*   ip = (int*)(ws + (size_t)M * 128);
    int*   rowptr  = ip;                                   // M+1
    int2*  packed  = (int2*)(ip + (((size_t)M + 4) & ~(size_t)3));  // E
    int*   tilesum = (int*)(packed + E);                   // 64
    int*   bcnt    = tilesum + 64;                         // NB
    int*   bbase   = bcnt + 1024;                          // NB+1
    int*   bcur    = bbase + 1032;                         // NB
    unsigned short* Wt0   = (unsigned short*)(bcur + 1024);    // [256][512]
    unsigned short* Wt1   = Wt0 + 256 * 512;                   // [128][256]
    unsigned short* Wg0t  = Wt1 + 128 * 256;                   // 7x [128][128]
    unsigned short* Wg1t  = Wg0t + 16384;
    unsigned short* Wembt = Wg1t + 16384;
    unsigned short* Wl0t  = Wembt + 16384;
    unsigned short* Wl1t  = Wl0t + 16384;
    unsigned short* Wr0t  = Wl1t + 16384;
    unsigned short* Wr1t  = Wr0t + 16384;

    // ---- d_out scratch timeline ----
    unsigned short* R0a = (unsigned short*)R0;
    unsigned short* R0b = (unsigned short*)R0 + (size_t)M * 128;
    unsigned short* R1a = (unsigned short*)R1;
    unsigned short* feat_bf = (unsigned short*)R0;  // [M,512] = R0+R1, dead after s1
    unsigned short* x1_bf   = (unsigned short*)R2;  // [M,256], dead after s2
    unsigned short* x_bf    = R0a;                  // s2 out; spmm3 src; s4 aux (feat_bf dead)
    unsigned short* h_bf    = R0b;                  // spmm3->s4 ; spmm5->s6
    unsigned short* n0_bf   = R1a;                  // s4 -> spmm5
    unsigned short* n1_bf   = R0a;                  // s6 -> s10/s8 (x_bf dead)
    unsigned short* rgt0_bf = R1a;                  // s10 -> s11 (n0 dead)
    unsigned short* lft0_bf = R0b;                  // s8 -> s9 (h dead)

    dim3 blk(256);
    const int gm128 = (M + 127) / 128;
    const int nch   = (E + RCHUNK - 1) / RCHUNK;

    // weight converts
    wconv<<<(512*256 + 255)/256, blk, 0, stream>>>(Wf0, Wt0, 512, 256);
    wconv<<<(256*128 + 255)/256, blk, 0, stream>>>(Wf1, Wt1, 256, 128);
    wconv<<<64, blk, 0, stream>>>(Wg,          Wg0t,  128, 128);
    wconv<<<64, blk, 0, stream>>>(Wg + 16384,  Wg1t,  128, 128);
    wconv<<<64, blk, 0, stream>>>(Wemb,        Wembt, 128, 128);
    wconv<<<64, blk, 0, stream>>>(Wl,          Wl0t,  128, 128);
    wconv<<<64, blk, 0, stream>>>(Wl + 16384,  Wl1t,  128, 128);
    wconv<<<64, blk, 0, stream>>>(Wr,          Wr0t,  128, 128);
    wconv<<<64, blk, 0, stream>>>(Wr + 16384,  Wr1t,  128, 128);

    // feat -> bf16 (into R0+R1; streams at HBM BW)
    f32_to_bf16<<<(int)(((long)M * 64 + 255) / 256), blk, 0, stream>>>(feat, feat_bf, (long)M * 64);

    // ---- CSR build: bucket pass + fused rowptr/place ----
    hipMemsetAsync(bcnt, 0, (size_t)NB * 4, stream);
    bhist_k<<<nch, blk, 0, stream>>>(srows, bcnt, E, NB);
    scan_phaseA<<<1, blk, 0, stream>>>(bcnt, tilesum, NB);
    scan_phaseB<<<1, 64, 0, stream>>>(tilesum, bbase, 1, NB);
    scan_phaseC<<<1, blk, 0, stream>>>(bcnt, tilesum, bbase, NB);
    init_bcur<<<(NB + 255)/256, blk, 0, stream>>>(bbase, bcur, NB);
    bucket_scatter<<<nch, blk, 0, stream>>>(srows, scols, svals, bcur, tmp, E, NB);
    csr_place<<<NB, blk, 0, stream>>>(tmp, bbase, rowptr, packed, M, NB);

    // ---- network ----
    // s1: x1_bf = tanh(feat @ Wf0 + bf0)
    mfma_big<<<dim3(gm128,2),blk,0,stream>>>(feat_bf, Wt0, bf0, x1_bf, M, 512, 256);
    // s2: x_bf = tanh(x1 @ Wf1 + bf1)
    mfma_big<<<dim3(gm128,1),blk,0,stream>>>(x1_bf, Wt1, bf1, x_bf, M, 256, 128);
    // spmm3: h_bf = S @ x
    spmm_csr<<<(M + 3) / 4, blk, 0, stream>>>(rowptr, packed, x_bf, h_bf, M);
    // s4: n0 = l2norm(tanh(h @ Wg0)) -> n0_bf; accf = x + n0
    mfma_ep<true,true,true,false,true,true,false,true,false><<<gm128,blk,0,stream>>>(
        h_bf, Wg0t, nullptr, nullptr, x_bf, accf, nullptr, n0_bf, M);
    // spmm5: h_bf = S @ n0
    spmm_csr<<<(M + 3) / 4, blk, 0, stream>>>(rowptr, packed, n0_bf, h_bf, M);
    // s6: n1 = l2norm(tanh(h @ Wg1)) -> n1_bf; accf += n1 (in-place)
    mfma_ep<true,true,true,false,true,false,false,true,false><<<gm128,blk,0,stream>>>(
        h_bf, Wg1t, nullptr, nullptr, accf, accf, nullptr, n1_bf, M);
    // s10: rgt0 = tanh(n1 @ Wr0 + br0) + n1 -> rgt0_bf
    mfma_ep<true,true,false,true,false,false,false,true,true><<<gm128,blk,0,stream>>>(
        n1_bf, Wr0t, br, n1_bf, nullptr, nullptr, nullptr, rgt0_bf, M);
    // s11: rgt = tanh(rgt0 @ Wr1 + br1) -> R2 final
    mfma_ep<true,true,false,false,false,false,true,false,true><<<gm128,blk,0,stream>>>(
        rgt0_bf, Wr1t, br + 128, nullptr, nullptr, nullptr, R2, nullptr, M);
    // s8: lft0 = tanh(n1 @ Wl0 + bl0) + n1 -> lft0_bf
    mfma_ep<true,true,false,true,false,false,false,true,true><<<gm128,blk,0,stream>>>(
        n1_bf, Wl0t, bl, n1_bf, nullptr, nullptr, nullptr, lft0_bf, M);
    // s9: lft = tanh(lft0 @ Wl1 + bl1) -> R1 final
    mfma_ep<true,true,false,false,false,false,true,false,true><<<gm128,blk,0,stream>>>(
        lft0_bf, Wl1t, bl + 128, nullptr, nullptr, nullptr, R1, nullptr, M);
    // s7: emb = l2norm(accf @ Wemb + bemb) -> R0 final (last: frees R0 scratch)
    mfma_ep<false,false,true,false,false,false,true,false,true><<<gm128,blk,0,stream>>>(
        accf, Wembt, bemb, nullptr, nullptr, nullptr, R0, nullptr, M);
}

// Round 9
// 931.591 us; speedup vs baseline: 1.2921x; 1.0230x over previous
//
#include <hip/hip_runtime.h>
#include <math.h>

typedef short bf16x8 __attribute__((ext_vector_type(8)));
typedef float f32x4  __attribute__((ext_vector_type(4)));

__device__ __forceinline__ unsigned short f2bf(float x) {
    unsigned u = __float_as_uint(x);
    unsigned r = u + 0x7FFFu + ((u >> 16) & 1u);   // RNE
    return (unsigned short)(r >> 16);
}
__device__ __forceinline__ float bf2f(unsigned short b) {
    return __uint_as_float(((unsigned)b) << 16);
}

// ============ weight convert+transpose: Wt[n][k] = bf16(W[k][n]) ============
__global__ __launch_bounds__(256)
void wconv(const float* __restrict__ W, unsigned short* __restrict__ Wt, int K, int N)
{
    int id = blockIdx.x * 256 + threadIdx.x;
    if (id >= K * N) return;
    int n = id / K, k = id - n * K;
    Wt[(size_t)n * K + k] = f2bf(W[(size_t)k * N + n]);
}

// ============ bulk f32 -> bf16 (for feat; streams at HBM BW) ============
__global__ __launch_bounds__(256)
void f32_to_bf16(const float* __restrict__ in, unsigned short* __restrict__ outb, long n8)
{
    long id = (long)blockIdx.x * 256 + threadIdx.x;   // one per 8 elems
    if (id >= n8) return;
    const float4* p = (const float4*)(in + id * 8);
    float4 a = p[0], b = p[1];
    *(ushort4*)(outb + id * 8)     = make_ushort4(f2bf(a.x), f2bf(a.y), f2bf(a.z), f2bf(a.w));
    *(ushort4*)(outb + id * 8 + 4) = make_ushort4(f2bf(b.x), f2bf(b.y), f2bf(b.z), f2bf(b.w));
}

// ============ MFMA GEMM: bf16 A, single-buffer LDS, BK=128, B from global ============
// A bf16 [M,K]; Wt bf16 [Ncols][K]. Tile 128x128, 4 waves 2x2.
// out: bf16 tanh(A@W + bias).
__global__ __launch_bounds__(256)
void mfma_big(const unsigned short* __restrict__ Ab, const unsigned short* __restrict__ Wt,
              const float* __restrict__ bias, unsigned short* __restrict__ out_bf,
              int M, int K, int Ncols)
{
    __shared__ __align__(16) unsigned short Al[128][136];   // 34.8 KB

    const int tid  = threadIdx.x;
    const int row0 = blockIdx.x * 128;
    const int col0 = blockIdx.y * 128;
    const int wv   = tid >> 6, lane = tid & 63;
    const int wr   = (wv >> 1) * 64, wc = (wv & 1) * 64;
    const int lr   = lane & 15;
    const int lk8  = (lane >> 4) * 8;

    f32x4 acc[4][4];
#pragma unroll
    for (int m = 0; m < 4; m++)
#pragma unroll
        for (int n = 0; n < 4; n++)
#pragma unroll
            for (int j = 0; j < 4; j++) acc[m][n][j] = 0.f;

    for (int k0 = 0; k0 < K; k0 += 128) {
        // stage 128 rows x 128 k: 2048 bf16x8 chunks, 8 per thread
#pragma unroll
        for (int i = 0; i < 8; i++) {
            int f = i * 256 + tid;
            int r = f >> 4, k8 = (f & 15) << 3;
            bf16x8 v = {0,0,0,0,0,0,0,0};
            if (row0 + r < M) v = *(const bf16x8*)(Ab + (size_t)(row0 + r) * K + k0 + k8);
            *(bf16x8*)&Al[r][k8] = v;
        }
        __syncthreads();
#pragma unroll
        for (int kk = 0; kk < 128; kk += 32) {
            bf16x8 af[4], bfr[4];
#pragma unroll
            for (int m = 0; m < 4; m++) af[m] = *(const bf16x8*)&Al[wr + m * 16 + lr][kk + lk8];
#pragma unroll
            for (int n = 0; n < 4; n++)
                bfr[n] = *(const bf16x8*)(Wt + (size_t)(col0 + wc + n * 16 + lr) * K + k0 + kk + lk8);
#pragma unroll
            for (int m = 0; m < 4; m++)
#pragma unroll
                for (int n = 0; n < 4; n++)
                    acc[m][n] = __builtin_amdgcn_mfma_f32_16x16x32_bf16(af[m], bfr[n], acc[m][n], 0, 0, 0);
        }
        __syncthreads();
    }

    const int rbase = (lane >> 4) * 4;
#pragma unroll
    for (int n = 0; n < 4; n++) {
        int col = col0 + wc + n * 16 + lr;
        float b = bias[col];
#pragma unroll
        for (int m = 0; m < 4; m++) {
#pragma unroll
            for (int j = 0; j < 4; j++) {
                int row = row0 + wr + m * 16 + rbase + j;
                if (row < M) out_bf[(size_t)row * Ncols + col] = f2bf(tanhf(acc[m][n][j] + b));
            }
        }
    }
}

// ============ MFMA K=128 single-tile with full fused epilogue ============
template<bool ABF16, bool TANH, bool L2, bool RESID, bool AUX, bool AUXBF,
         bool F32OUT, bool BF16OUT, bool BIAS>
__global__ __launch_bounds__(256)
void mfma_ep(const void* __restrict__ A_, const unsigned short* __restrict__ Wt,
             const float* __restrict__ bias, const unsigned short* __restrict__ resid_bf,
             const void* __restrict__ aux_in, float* __restrict__ aux_out,
             float* __restrict__ out, unsigned short* __restrict__ out_bf, int M)
{
    __shared__ __align__(16) unsigned short Al[128][136];   // 34.8 KB

    const int tid  = threadIdx.x;
    const int row0 = blockIdx.x * 128;
    const int wv   = tid >> 6, lane = tid & 63;
    const int lr   = lane & 15;
    const int lk8  = (lane >> 4) * 8;
    const int wr   = wv * 32;

    if (ABF16) {
        const unsigned short* Ab = (const unsigned short*)A_;
#pragma unroll
        for (int i = 0; i < 8; i++) {
            int f = i * 256 + tid;
            int r = f >> 4, k8 = (f & 15) << 3;
            bf16x8 v = {0,0,0,0,0,0,0,0};
            if (row0 + r < M) v = *(const bf16x8*)(Ab + ((size_t)(row0 + r) << 7) + k8);
            *(bf16x8*)&Al[r][k8] = v;
        }
    } else {
        const float* Af = (const float*)A_;
#pragma unroll
        for (int i = 0; i < 16; i++) {
            int f = i * 256 + tid;
            int r = f >> 5, c4 = (f & 31) << 2;
            float4 a = make_float4(0.f, 0.f, 0.f, 0.f);
            if (row0 + r < M) a = *(const float4*)(Af + ((size_t)(row0 + r) << 7) + c4);
            *(ushort4*)&Al[r][c4] = make_ushort4(f2bf(a.x), f2bf(a.y), f2bf(a.z), f2bf(a.w));
        }
    }
    __syncthreads();

    f32x4 acc[2][8];
#pragma unroll
    for (int m = 0; m < 2; m++)
#pragma unroll
        for (int n = 0; n < 8; n++)
#pragma unroll
            for (int j = 0; j < 4; j++) acc[m][n][j] = 0.f;

#pragma unroll 1
    for (int ks = 0; ks < 4; ks++) {
        bf16x8 af[2], bn[8];
#pragma unroll
        for (int m = 0; m < 2; m++) af[m] = *(const bf16x8*)&Al[wr + m * 16 + lr][ks * 32 + lk8];
#pragma unroll
        for (int n = 0; n < 8; n++)
            bn[n] = *(const bf16x8*)(Wt + (((size_t)(n * 16 + lr)) << 7) + ks * 32 + lk8);
#pragma unroll
        for (int m = 0; m < 2; m++)
#pragma unroll
            for (int n = 0; n < 8; n++)
                acc[m][n] = __builtin_amdgcn_mfma_f32_16x16x32_bf16(af[m], bn[n], acc[m][n], 0, 0, 0);
    }

    const int rbase = (lane >> 4) * 4;
    float bv[8];
#pragma unroll
    for (int n = 0; n < 8; n++) bv[n] = BIAS ? bias[n * 16 + lr] : 0.f;

#pragma unroll
    for (int m = 0; m < 2; m++) {
#pragma unroll
        for (int j = 0; j < 4; j++) {
            int row = row0 + wr + m * 16 + rbase + j;
            bool ok = row < M;
            float v[8];
#pragma unroll
            for (int n = 0; n < 8; n++) {
                v[n] = acc[m][n][j] + bv[n];
                if (TANH) v[n] = tanhf(v[n]);
            }
            if (RESID) {
#pragma unroll
                for (int n = 0; n < 8; n++)
                    if (ok) v[n] += bf2f(resid_bf[((size_t)row << 7) + n * 16 + lr]);
            }
            if (L2) {
                float s = 0.f;
#pragma unroll
                for (int n = 0; n < 8; n++) s += v[n] * v[n];
#pragma unroll
                for (int msk = 8; msk >= 1; msk >>= 1) s += __shfl_xor(s, msk);
                float sc = 1.f / fmaxf(sqrtf(s), 1e-12f);
#pragma unroll
                for (int n = 0; n < 8; n++) v[n] *= sc;
            }
            if (ok) {
#pragma unroll
                for (int n = 0; n < 8; n++) {
                    size_t off = ((size_t)row << 7) + n * 16 + lr;
                    if (F32OUT)  out[off] = v[n];
                    if (BF16OUT) out_bf[off] = f2bf(v[n]);
                    if (AUX) {
                        float ai = AUXBF ? bf2f(((const unsigned short*)aux_in)[off])
                                         : ((const float*)aux_in)[off];
                        aux_out[off] = ai + v[n];
                    }
                }
            }
        }
    }
}

// ============ scan helpers (bucket-level only, NB<=2048) ============
#define SCAN_TILE 2048

__global__ __launch_bounds__(256)
void scan_phaseA(const int* __restrict__ cnt, int* __restrict__ tilesum, int N)
{
    __shared__ int sdata[256];
    int base = blockIdx.x * SCAN_TILE + threadIdx.x * 8;
    int s = 0;
#pragma unroll
    for (int j = 0; j < 8; j++) { int i = base + j; if (i < N) s += cnt[i]; }
    sdata[threadIdx.x] = s; __syncthreads();
    for (int off = 128; off > 0; off >>= 1) {
        if (threadIdx.x < off) sdata[threadIdx.x] += sdata[threadIdx.x + off];
        __syncthreads();
    }
    if (threadIdx.x == 0) tilesum[blockIdx.x] = sdata[0];
}

__global__ void scan_phaseB(int* __restrict__ tilesum, int* __restrict__ rowptr,
                            int numTiles, int N)
{
    if (threadIdx.x == 0 && blockIdx.x == 0) {
        int run = 0;
        for (int t = 0; t < numTiles; t++) { int v = tilesum[t]; tilesum[t] = run; run += v; }
        rowptr[N] = run;
    }
}

__global__ __launch_bounds__(256)
void scan_phaseC(const int* __restrict__ cnt, const int* __restrict__ tilesum,
                 int* __restrict__ rowptr, int N)
{
    __shared__ int sdata[256];
    int base = blockIdx.x * SCAN_TILE + threadIdx.x * 8;
    int loc[8]; int s = 0;
#pragma unroll
    for (int j = 0; j < 8; j++) {
        int i = base + j; int v = (i < N) ? cnt[i] : 0;
        loc[j] = s; s += v;
    }
    sdata[threadIdx.x] = s; __syncthreads();
    int x = s;
    for (int off = 1; off < 256; off <<= 1) {
        int t = 0;
        if (threadIdx.x >= off) t = sdata[threadIdx.x - off];
        __syncthreads();
        x += t;
        sdata[threadIdx.x] = x;
        __syncthreads();
    }
    int texcl = x - s + tilesum[blockIdx.x];
#pragma unroll
    for (int j = 0; j < 8; j++) {
        int i = base + j;
        if (i < N) rowptr[i] = texcl + loc[j];
    }
}

// ============ bucketed reorder (no line-thrashing scatter) ============
#define RCHUNK 16384

__global__ __launch_bounds__(256)
void bhist_k(const int* __restrict__ rows, int* __restrict__ bcnt, int E, int NB)
{
    __shared__ int lc[1024];
    for (int b = threadIdx.x; b < NB; b += 256) lc[b] = 0;
    __syncthreads();
    int start = blockIdx.x * RCHUNK;
    int end = min(start + RCHUNK, E);
    for (int i = start + threadIdx.x; i < end; i += 256)
        atomicAdd(&lc[rows[i] >> 7], 1);
    __syncthreads();
    for (int b = threadIdx.x; b < NB; b += 256)
        if (lc[b]) atomicAdd(&bcnt[b], lc[b]);
}

__global__ void init_bcur(const int* __restrict__ bbase, int* __restrict__ bcur, int NB)
{
    int b = blockIdx.x * 256 + threadIdx.x;
    if (b < NB) bcur[b] = bbase[b];
}

// group edges by 128-row bucket; run-reserved coalesced writes; row_low in col bits 17..23
__global__ __launch_bounds__(256)
void bucket_scatter(const int* __restrict__ rows, const int* __restrict__ cols,
                    const float* __restrict__ vals, int* __restrict__ bcur,
                    int2* __restrict__ tmp, int E, int NB)
{
    __shared__ int lcnt[1024];
    __shared__ int lbase[1024];
    for (int b = threadIdx.x; b < NB; b += 256) lcnt[b] = 0;
    __syncthreads();
    int start = blockIdx.x * RCHUNK;
    int end = min(start + RCHUNK, E);
    for (int i = start + threadIdx.x; i < end; i += 256)
        atomicAdd(&lcnt[rows[i] >> 7], 1);
    __syncthreads();
    for (int b = threadIdx.x; b < NB; b += 256) {
        int c = lcnt[b];
        lbase[b] = c ? atomicAdd(&bcur[b], c) : 0;
        lcnt[b] = 0;
    }
    __syncthreads();
    for (int i = start + threadIdx.x; i < end; i += 256) {
        int r = rows[i];
        int b = r >> 7;
        int off = atomicAdd(&lcnt[b], 1);
        tmp[lbase[b] + off] = make_int2(cols[i] | ((r & 127) << 17), __float_as_int(vals[i]));
    }
}

// one block per bucket: local row-count + scan -> writes rowptr AND places edges
__global__ __launch_bounds__(256)
void csr_place(const int2* __restrict__ tmp, const int* __restrict__ bbase,
               int* __restrict__ rowptr, int2* __restrict__ packed, int M, int NB)
{
    __shared__ int lcnt[128];
    __shared__ int lofs[128];
    const int tid = threadIdx.x;
    const int b = blockIdx.x;
    const int s = bbase[b], e = bbase[b + 1];
    const int rb = b << 7;
    if (tid < 128) lcnt[tid] = 0;
    __syncthreads();
    for (int i = s + tid; i < e; i += 256)
        atomicAdd(&lcnt[(((unsigned)tmp[i].x) >> 17) & 127], 1);
    __syncthreads();
    if (tid == 0) {
        int run = s;
#pragma unroll 8
        for (int r = 0; r < 128; r++) { lofs[r] = run; run += lcnt[r]; }
    }
    __syncthreads();
    if (tid < 128 && rb + tid < M) rowptr[rb + tid] = lofs[tid];
    if (b == NB - 1 && tid == 0) rowptr[M] = e;
    if (tid < 128) lcnt[tid] = 0;
    __syncthreads();
    for (int i = s + tid; i < e; i += 256) {
        int2 t = tmp[i];
        int rl = (((unsigned)t.x) >> 17) & 127;
        int pos = lofs[rl] + atomicAdd(&lcnt[rl], 1);
        packed[pos] = make_int2(t.x & 0x1FFFF, t.y);
    }
}

// ============ CSR SpMM: 16 lanes/edge x 4 edge-groups, 16B gathers ============
// wave per row; group g handles edges s+g, s+g+4, ...; lane covers cols q*8..q*8+7.
__global__ __launch_bounds__(256)
void spmm_csr(const int* __restrict__ rowptr, const int2* __restrict__ packed,
              const unsigned short* __restrict__ embb, unsigned short* __restrict__ hb, int N)
{
    const int wv = threadIdx.x >> 6, lane = threadIdx.x & 63;
    const int g = lane >> 4, q = lane & 15;
    const int r = blockIdx.x * 4 + wv;
    if (r >= N) return;
    const int s = rowptr[r], e = rowptr[r + 1];
    const unsigned short* __restrict__ eb = embb + q * 8;

    float a0=0.f,a1=0.f,a2=0.f,a3=0.f,a4=0.f,a5=0.f,a6=0.f,a7=0.f;
    int i = s + g;
    for (; i + 12 < e; i += 16) {          // 4 edges per group per pass (16 in flight/wave)
#pragma unroll
        for (int u = 0; u < 4; u++) {
            int2 p = packed[i + 4 * u];
            uint4 m = *(const uint4*)(eb + ((size_t)p.x << 7));
            float v = __int_as_float(p.y);
            a0 += v * __uint_as_float(m.x << 16);
            a1 += v * __uint_as_float(m.x & 0xffff0000u);
            a2 += v * __uint_as_float(m.y << 16);
            a3 += v * __uint_as_float(m.y & 0xffff0000u);
            a4 += v * __uint_as_float(m.z << 16);
            a5 += v * __uint_as_float(m.z & 0xffff0000u);
            a6 += v * __uint_as_float(m.w << 16);
            a7 += v * __uint_as_float(m.w & 0xffff0000u);
        }
    }
    for (; i < e; i += 4) {
        int2 p = packed[i];
        uint4 m = *(const uint4*)(eb + ((size_t)p.x << 7));
        float v = __int_as_float(p.y);
        a0 += v * __uint_as_float(m.x << 16);
        a1 += v * __uint_as_float(m.x & 0xffff0000u);
        a2 += v * __uint_as_float(m.y << 16);
        a3 += v * __uint_as_float(m.y & 0xffff0000u);
        a4 += v * __uint_as_float(m.z << 16);
        a5 += v * __uint_as_float(m.z & 0xffff0000u);
        a6 += v * __uint_as_float(m.w << 16);
        a7 += v * __uint_as_float(m.w & 0xffff0000u);
    }
    // combine the 4 edge-groups (lane bits 4,5)
#pragma unroll
    for (int msk = 16; msk <= 32; msk <<= 1) {
        a0 += __shfl_xor(a0, msk); a1 += __shfl_xor(a1, msk);
        a2 += __shfl_xor(a2, msk); a3 += __shfl_xor(a3, msk);
        a4 += __shfl_xor(a4, msk); a5 += __shfl_xor(a5, msk);
        a6 += __shfl_xor(a6, msk); a7 += __shfl_xor(a7, msk);
    }
    if (g == 0) {
        unsigned o0 = (unsigned)f2bf(a0) | ((unsigned)f2bf(a1) << 16);
        unsigned o1 = (unsigned)f2bf(a2) | ((unsigned)f2bf(a3) << 16);
        unsigned o2 = (unsigned)f2bf(a4) | ((unsigned)f2bf(a5) << 16);
        unsigned o3 = (unsigned)f2bf(a6) | ((unsigned)f2bf(a7) << 16);
        *(uint4*)(hb + ((size_t)r << 7) + q * 8) = make_uint4(o0, o1, o2, o3);
    }
}

// ============ launch ============
extern "C" void kernel_launch(void* const* d_in, const int* in_sizes, int n_in,
                              void* d_out, int out_size, void* d_ws, size_t ws_size,
                              hipStream_t stream)
{
    const float* feat  = (const float*)d_in[0];
    const int*   srows = (const int*)  d_in[1];
    const int*   scols = (const int*)  d_in[2];
    const float* svals = (const float*)d_in[3];
    const float* Wf0   = (const float*)d_in[4];
    const float* bf0   = (const float*)d_in[5];
    const float* Wf1   = (const float*)d_in[6];
    const float* bf1   = (const float*)d_in[7];
    const float* Wg    = (const float*)d_in[8];
    const float* Wemb  = (const float*)d_in[9];
    const float* bemb  = (const float*)d_in[10];
    const float* Wl    = (const float*)d_in[11];
    const float* bl    = (const float*)d_in[12];
    const float* Wr    = (const float*)d_in[13];
    const float* br    = (const float*)d_in[14];

    const int M = in_sizes[0] / 512;   // 100000 nodes
    const int E = in_sizes[1];         // 3200000 edges
    const int NB = (M + 127) >> 7;     // 782 buckets

    float* out = (float*)d_out;
    float* R0 = out;                        // emb final
    float* R1 = out + (size_t)M * 128;      // lft final
    float* R2 = out + (size_t)M * 256;      // rgt final

    // ---- ws layout ----
    float* ws = (float*)d_ws;
    float* accf = ws;                                      // [M,128] f32 gnn_acc; tmp aliases
    int2*  tmp  = (int2*)ws;                               // [E] int2, dead before s4
    int*   ip = (int*)(ws + (size_t)M * 128);
    int*   rowptr  = ip;                                   // M+1
    int2*  packed  = (int2*)(ip + (((size_t)M + 4) & ~(size_t)3));  // E
    int*   tilesum = (int*)(packed + E);                   // 64
    int*   bcnt    = tilesum + 64;                         // NB
    int*   bbase   = bcnt + 1024;                          // NB+1
    int*   bcur    = bbase + 1032;                         // NB
    unsigned short* Wt0   = (unsigned short*)(bcur + 1024);    // [256][512]
    unsigned short* Wt1   = Wt0 + 256 * 512;                   // [128][256]
    unsigned short* Wg0t  = Wt1 + 128 * 256;                   // 7x [128][128]
    unsigned short* Wg1t  = Wg0t + 16384;
    unsigned short* Wembt = Wg1t + 16384;
    unsigned short* Wl0t  = Wembt + 16384;
    unsigned short* Wl1t  = Wl0t + 16384;
    unsigned short* Wr0t  = Wl1t + 16384;
    unsigned short* Wr1t  = Wr0t + 16384;

    // ---- d_out scratch timeline ----
    unsigned short* R0a = (unsigned short*)R0;
    unsigned short* R0b = (unsigned short*)R0 + (size_t)M * 128;
    unsigned short* R1a = (unsigned short*)R1;
    unsigned short* feat_bf = (unsigned short*)R0;  // [M,512] = R0+R1, dead after s1
    unsigned short* x1_bf   = (unsigned short*)R2;  // [M,256], dead after s2
    unsigned short* x_bf    = R0a;                  // s2 out; spmm3 src; s4 aux (feat_bf dead)
    unsigned short* h_bf    = R0b;                  // spmm3->s4 ; spmm5->s6
    unsigned short* n0_bf   = R1a;                  // s4 -> spmm5
    unsigned short* n1_bf   = R0a;                  // s6 -> s10/s8 (x_bf dead)
    unsigned short* rgt0_bf = R1a;                  // s10 -> s11 (n0 dead)
    unsigned short* lft0_bf = R0b;                  // s8 -> s9 (h dead)

    dim3 blk(256);
    const int gm128 = (M + 127) / 128;
    const int nch   = (E + RCHUNK - 1) / RCHUNK;

    // weight converts
    wconv<<<(512*256 + 255)/256, blk, 0, stream>>>(Wf0, Wt0, 512, 256);
    wconv<<<(256*128 + 255)/256, blk, 0, stream>>>(Wf1, Wt1, 256, 128);
    wconv<<<64, blk, 0, stream>>>(Wg,          Wg0t,  128, 128);
    wconv<<<64, blk, 0, stream>>>(Wg + 16384,  Wg1t,  128, 128);
    wconv<<<64, blk, 0, stream>>>(Wemb,        Wembt, 128, 128);
    wconv<<<64, blk, 0, stream>>>(Wl,          Wl0t,  128, 128);
    wconv<<<64, blk, 0, stream>>>(Wl + 16384,  Wl1t,  128, 128);
    wconv<<<64, blk, 0, stream>>>(Wr,          Wr0t,  128, 128);
    wconv<<<64, blk, 0, stream>>>(Wr + 16384,  Wr1t,  128, 128);

    // feat -> bf16 (into R0+R1; streams at HBM BW)
    f32_to_bf16<<<(int)(((long)M * 64 + 255) / 256), blk, 0, stream>>>(feat, feat_bf, (long)M * 64);

    // ---- CSR build: bucket pass + fused rowptr/place ----
    hipMemsetAsync(bcnt, 0, (size_t)NB * 4, stream);
    bhist_k<<<nch, blk, 0, stream>>>(srows, bcnt, E, NB);
    scan_phaseA<<<1, blk, 0, stream>>>(bcnt, tilesum, NB);
    scan_phaseB<<<1, 64, 0, stream>>>(tilesum, bbase, 1, NB);
    scan_phaseC<<<1, blk, 0, stream>>>(bcnt, tilesum, bbase, NB);
    init_bcur<<<(NB + 255)/256, blk, 0, stream>>>(bbase, bcur, NB);
    bucket_scatter<<<nch, blk, 0, stream>>>(srows, scols, svals, bcur, tmp, E, NB);
    csr_place<<<NB, blk, 0, stream>>>(tmp, bbase, rowptr, packed, M, NB);

    // ---- network ----
    // s1: x1_bf = tanh(feat @ Wf0 + bf0)
    mfma_big<<<dim3(gm128,2),blk,0,stream>>>(feat_bf, Wt0, bf0, x1_bf, M, 512, 256);
    // s2: x_bf = tanh(x1 @ Wf1 + bf1)
    mfma_big<<<dim3(gm128,1),blk,0,stream>>>(x1_bf, Wt1, bf1, x_bf, M, 256, 128);
    // spmm3: h_bf = S @ x
    spmm_csr<<<(M + 3) / 4, blk, 0, stream>>>(rowptr, packed, x_bf, h_bf, M);
    // s4: n0 = l2norm(tanh(h @ Wg0)) -> n0_bf; accf = x + n0
    mfma_ep<true,true,true,false,true,true,false,true,false><<<gm128,blk,0,stream>>>(
        h_bf, Wg0t, nullptr, nullptr, x_bf, accf, nullptr, n0_bf, M);
    // spmm5: h_bf = S @ n0
    spmm_csr<<<(M + 3) / 4, blk, 0, stream>>>(rowptr, packed, n0_bf, h_bf, M);
    // s6: n1 = l2norm(tanh(h @ Wg1)) -> n1_bf; accf += n1 (in-place)
    mfma_ep<true,true,true,false,true,false,false,true,false><<<gm128,blk,0,stream>>>(
        h_bf, Wg1t, nullptr, nullptr, accf, accf, nullptr, n1_bf, M);
    // s10: rgt0 = tanh(n1 @ Wr0 + br0) + n1 -> rgt0_bf
    mfma_ep<true,true,false,true,false,false,false,true,true><<<gm128,blk,0,stream>>>(
        n1_bf, Wr0t, br, n1_bf, nullptr, nullptr, nullptr, rgt0_bf, M);
    // s11: rgt = tanh(rgt0 @ Wr1 + br1) -> R2 final
    mfma_ep<true,true,false,false,false,false,true,false,true><<<gm128,blk,0,stream>>>(
        rgt0_bf, Wr1t, br + 128, nullptr, nullptr, nullptr, R2, nullptr, M);
    // s8: lft0 = tanh(n1 @ Wl0 + bl0) + n1 -> lft0_bf
    mfma_ep<true,true,false,true,false,false,false,true,true><<<gm128,blk,0,stream>>>(
        n1_bf, Wl0t, bl, n1_bf, nullptr, nullptr, nullptr, lft0_bf, M);
    // s9: lft = tanh(lft0 @ Wl1 + bl1) -> R1 final
    mfma_ep<true,true,false,false,false,false,true,false,true><<<gm128,blk,0,stream>>>(
        lft0_bf, Wl1t, bl + 128, nullptr, nullptr, nullptr, R1, nullptr, M);
    // s7: emb = l2norm(accf @ Wemb + bemb) -> R0 final (last: frees R0 scratch)
    mfma_ep<false,false,true,false,false,false,true,false,true><<<gm128,blk,0,stream>>>(
        accf, Wembt, bemb, nullptr, nullptr, nullptr, R0, nullptr, M);
}

// Round 10
// 921.315 us; speedup vs baseline: 1.3065x; 1.0112x over previous
//
#include <hip/hip_runtime.h>
#include <math.h>

typedef short bf16x8 __attribute__((ext_vector_type(8)));
typedef float f32x4  __attribute__((ext_vector_type(4)));

__device__ __forceinline__ unsigned short f2bf(float x) {
    unsigned u = __float_as_uint(x);
    unsigned r = u + 0x7FFFu + ((u >> 16) & 1u);   // RNE
    return (unsigned short)(r >> 16);
}
__device__ __forceinline__ float bf2f(unsigned short b) {
    return __uint_as_float(((unsigned)b) << 16);
}
__device__ __forceinline__ bf16x8 ld_f32x8_as_bf(const float* p) {
    float4 a = *(const float4*)p;
    float4 b = *(const float4*)(p + 4);
    bf16x8 v;
    v[0] = (short)f2bf(a.x); v[1] = (short)f2bf(a.y);
    v[2] = (short)f2bf(a.z); v[3] = (short)f2bf(a.w);
    v[4] = (short)f2bf(b.x); v[5] = (short)f2bf(b.y);
    v[6] = (short)f2bf(b.z); v[7] = (short)f2bf(b.w);
    return v;
}

// ============ weight convert+transpose: Wt[n][k] = bf16(W[k][n]) ============
__global__ __launch_bounds__(256)
void wconv(const float* __restrict__ W, unsigned short* __restrict__ Wt, int K, int N)
{
    int id = blockIdx.x * 256 + threadIdx.x;
    if (id >= K * N) return;
    int n = id / K, k = id - n * K;
    Wt[(size_t)n * K + k] = f2bf(W[(size_t)k * N + n]);
}

// ============ bulk f32 -> bf16 (for feat; streams at HBM BW) ============
__global__ __launch_bounds__(256)
void f32_to_bf16(const float* __restrict__ in, unsigned short* __restrict__ outb, long n8)
{
    long id = (long)blockIdx.x * 256 + threadIdx.x;   // one per 8 elems
    if (id >= n8) return;
    const float4* p = (const float4*)(in + id * 8);
    float4 a = p[0], b = p[1];
    *(ushort4*)(outb + id * 8)     = make_ushort4(f2bf(a.x), f2bf(a.y), f2bf(a.z), f2bf(a.w));
    *(ushort4*)(outb + id * 8 + 4) = make_ushort4(f2bf(b.x), f2bf(b.y), f2bf(b.z), f2bf(b.w));
}

// ============ LDS-free MFMA GEMM: direct fragment loads, no barriers ============
// A bf16 [M,K]; Wt bf16 [Ncols][K]. Block = 4 waves 2x2 of 64x64 -> 128x128 tile.
// A-fragment loads: 4-lane groups read 64B contiguous per row (line-coalesced).
// OOB rows clamped to M-1 (loaded garbage never stored). out = bf16 tanh(A@W+bias).
__global__ __launch_bounds__(256)
void mfma_direct(const unsigned short* __restrict__ Ab, const unsigned short* __restrict__ Wt,
                 const float* __restrict__ bias, unsigned short* __restrict__ out_bf,
                 int M, int K, int Ncols)
{
    const int tid  = threadIdx.x;
    const int row0 = blockIdx.x * 128;
    const int col0 = blockIdx.y * 128;
    const int wv   = tid >> 6, lane = tid & 63;
    const int wr   = (wv >> 1) * 64, wc = (wv & 1) * 64;
    const int lr   = lane & 15;
    const int lk8  = (lane >> 4) * 8;

    const unsigned short* arow[4];
    const unsigned short* brow[4];
#pragma unroll
    for (int m = 0; m < 4; m++) {
        int r = row0 + wr + m * 16 + lr;
        r = r < M ? r : (M - 1);
        arow[m] = Ab + (size_t)r * K + lk8;
    }
#pragma unroll
    for (int n = 0; n < 4; n++)
        brow[n] = Wt + (size_t)(col0 + wc + n * 16 + lr) * K + lk8;

    f32x4 acc[4][4];
#pragma unroll
    for (int m = 0; m < 4; m++)
#pragma unroll
        for (int n = 0; n < 4; n++)
#pragma unroll
            for (int j = 0; j < 4; j++) acc[m][n][j] = 0.f;

#pragma unroll 2
    for (int kk = 0; kk < K; kk += 32) {
        bf16x8 af[4], bfr[4];
#pragma unroll
        for (int m = 0; m < 4; m++) af[m]  = *(const bf16x8*)(arow[m] + kk);
#pragma unroll
        for (int n = 0; n < 4; n++) bfr[n] = *(const bf16x8*)(brow[n] + kk);
#pragma unroll
        for (int m = 0; m < 4; m++)
#pragma unroll
            for (int n = 0; n < 4; n++)
                acc[m][n] = __builtin_amdgcn_mfma_f32_16x16x32_bf16(af[m], bfr[n], acc[m][n], 0, 0, 0);
    }

    const int rbase = (lane >> 4) * 4;
#pragma unroll
    for (int n = 0; n < 4; n++) {
        int col = col0 + wc + n * 16 + lr;
        float b = bias[col];
#pragma unroll
        for (int m = 0; m < 4; m++) {
#pragma unroll
            for (int j = 0; j < 4; j++) {
                int row = row0 + wr + m * 16 + rbase + j;
                if (row < M) out_bf[(size_t)row * Ncols + col] = f2bf(tanhf(acc[m][n][j] + b));
            }
        }
    }
}

// ============ LDS-free MFMA K=128 single-tile with full fused epilogue ============
// Block = 128 rows; wave = 32 rows x 128 cols. No LDS, no barriers.
template<bool ABF16, bool TANH, bool L2, bool RESID, bool AUX, bool AUXBF,
         bool F32OUT, bool BF16OUT, bool BIAS>
__global__ __launch_bounds__(256)
void mfma_ep(const void* __restrict__ A_, const unsigned short* __restrict__ Wt,
             const float* __restrict__ bias, const unsigned short* __restrict__ resid_bf,
             const void* __restrict__ aux_in, float* __restrict__ aux_out,
             float* __restrict__ out, unsigned short* __restrict__ out_bf, int M)
{
    const int tid  = threadIdx.x;
    const int row0 = blockIdx.x * 128;
    const int wv   = tid >> 6, lane = tid & 63;
    const int lr   = lane & 15;
    const int lk8  = (lane >> 4) * 8;
    const int wr   = wv * 32;

    // clamped per-m A row bases
    const unsigned short* Abr[2];
    const float*          Afr[2];
#pragma unroll
    for (int m = 0; m < 2; m++) {
        int r = row0 + wr + m * 16 + lr;
        r = r < M ? r : (M - 1);
        if (ABF16) Abr[m] = (const unsigned short*)A_ + ((size_t)r << 7) + lk8;
        else       Afr[m] = (const float*)A_          + ((size_t)r << 7) + lk8;
    }

    f32x4 acc[2][8];
#pragma unroll
    for (int m = 0; m < 2; m++)
#pragma unroll
        for (int n = 0; n < 8; n++)
#pragma unroll
            for (int j = 0; j < 4; j++) acc[m][n][j] = 0.f;

#pragma unroll 2
    for (int ks = 0; ks < 4; ks++) {
        bf16x8 af[2], bn[8];
#pragma unroll
        for (int m = 0; m < 2; m++) {
            if (ABF16) af[m] = *(const bf16x8*)(Abr[m] + ks * 32);
            else       af[m] = ld_f32x8_as_bf(Afr[m] + ks * 32);
        }
#pragma unroll
        for (int n = 0; n < 8; n++)
            bn[n] = *(const bf16x8*)(Wt + (((size_t)(n * 16 + lr)) << 7) + ks * 32 + lk8);
#pragma unroll
        for (int m = 0; m < 2; m++)
#pragma unroll
            for (int n = 0; n < 8; n++)
                acc[m][n] = __builtin_amdgcn_mfma_f32_16x16x32_bf16(af[m], bn[n], acc[m][n], 0, 0, 0);
    }

    const int rbase = (lane >> 4) * 4;
    float bv[8];
#pragma unroll
    for (int n = 0; n < 8; n++) bv[n] = BIAS ? bias[n * 16 + lr] : 0.f;

#pragma unroll
    for (int m = 0; m < 2; m++) {
#pragma unroll
        for (int j = 0; j < 4; j++) {
            int row = row0 + wr + m * 16 + rbase + j;
            bool ok = row < M;
            float v[8];
#pragma unroll
            for (int n = 0; n < 8; n++) {
                v[n] = acc[m][n][j] + bv[n];
                if (TANH) v[n] = tanhf(v[n]);
            }
            if (RESID) {
#pragma unroll
                for (int n = 0; n < 8; n++)
                    if (ok) v[n] += bf2f(resid_bf[((size_t)row << 7) + n * 16 + lr]);
            }
            if (L2) {
                float s = 0.f;
#pragma unroll
                for (int n = 0; n < 8; n++) s += v[n] * v[n];
#pragma unroll
                for (int msk = 8; msk >= 1; msk >>= 1) s += __shfl_xor(s, msk);
                float sc = 1.f / fmaxf(sqrtf(s), 1e-12f);
#pragma unroll
                for (int n = 0; n < 8; n++) v[n] *= sc;
            }
            if (ok) {
#pragma unroll
                for (int n = 0; n < 8; n++) {
                    size_t off = ((size_t)row << 7) + n * 16 + lr;
                    if (F32OUT)  out[off] = v[n];
                    if (BF16OUT) out_bf[off] = f2bf(v[n]);
                    if (AUX) {
                        float ai = AUXBF ? bf2f(((const unsigned short*)aux_in)[off])
                                         : ((const float*)aux_in)[off];
                        aux_out[off] = ai + v[n];
                    }
                }
            }
        }
    }
}

// ============ scan helpers (bucket-level only, NB<=2048) ============
#define SCAN_TILE 2048

__global__ __launch_bounds__(256)
void scan_phaseA(const int* __restrict__ cnt, int* __restrict__ tilesum, int N)
{
    __shared__ int sdata[256];
    int base = blockIdx.x * SCAN_TILE + threadIdx.x * 8;
    int s = 0;
#pragma unroll
    for (int j = 0; j < 8; j++) { int i = base + j; if (i < N) s += cnt[i]; }
    sdata[threadIdx.x] = s; __syncthreads();
    for (int off = 128; off > 0; off >>= 1) {
        if (threadIdx.x < off) sdata[threadIdx.x] += sdata[threadIdx.x + off];
        __syncthreads();
    }
    if (threadIdx.x == 0) tilesum[blockIdx.x] = sdata[0];
}

__global__ void scan_phaseB(int* __restrict__ tilesum, int* __restrict__ rowptr,
                            int numTiles, int N)
{
    if (threadIdx.x == 0 && blockIdx.x == 0) {
        int run = 0;
        for (int t = 0; t < numTiles; t++) { int v = tilesum[t]; tilesum[t] = run; run += v; }
        rowptr[N] = run;
    }
}

__global__ __launch_bounds__(256)
void scan_phaseC(const int* __restrict__ cnt, const int* __restrict__ tilesum,
                 int* __restrict__ rowptr, int N)
{
    __shared__ int sdata[256];
    int base = blockIdx.x * SCAN_TILE + threadIdx.x * 8;
    int loc[8]; int s = 0;
#pragma unroll
    for (int j = 0; j < 8; j++) {
        int i = base + j; int v = (i < N) ? cnt[i] : 0;
        loc[j] = s; s += v;
    }
    sdata[threadIdx.x] = s; __syncthreads();
    int x = s;
    for (int off = 1; off < 256; off <<= 1) {
        int t = 0;
        if (threadIdx.x >= off) t = sdata[threadIdx.x - off];
        __syncthreads();
        x += t;
        sdata[threadIdx.x] = x;
        __syncthreads();
    }
    int texcl = x - s + tilesum[blockIdx.x];
#pragma unroll
    for (int j = 0; j < 8; j++) {
        int i = base + j;
        if (i < N) rowptr[i] = texcl + loc[j];
    }
}

// ============ bucketed reorder (no line-thrashing scatter) ============
#define RCHUNK 16384

__global__ __launch_bounds__(256)
void bhist_k(const int* __restrict__ rows, int* __restrict__ bcnt, int E, int NB)
{
    __shared__ int lc[1024];
    for (int b = threadIdx.x; b < NB; b += 256) lc[b] = 0;
    __syncthreads();
    int start = blockIdx.x * RCHUNK;
    int end = min(start + RCHUNK, E);
    for (int i = start + threadIdx.x; i < end; i += 256)
        atomicAdd(&lc[rows[i] >> 7], 1);
    __syncthreads();
    for (int b = threadIdx.x; b < NB; b += 256)
        if (lc[b]) atomicAdd(&bcnt[b], lc[b]);
}

__global__ void init_bcur(const int* __restrict__ bbase, int* __restrict__ bcur, int NB)
{
    int b = blockIdx.x * 256 + threadIdx.x;
    if (b < NB) bcur[b] = bbase[b];
}

// group edges by 128-row bucket; run-reserved coalesced writes; row_low in col bits 17..23
__global__ __launch_bounds__(256)
void bucket_scatter(const int* __restrict__ rows, const int* __restrict__ cols,
                    const float* __restrict__ vals, int* __restrict__ bcur,
                    int2* __restrict__ tmp, int E, int NB)
{
    __shared__ int lcnt[1024];
    __shared__ int lbase[1024];
    for (int b = threadIdx.x; b < NB; b += 256) lcnt[b] = 0;
    __syncthreads();
    int start = blockIdx.x * RCHUNK;
    int end = min(start + RCHUNK, E);
    for (int i = start + threadIdx.x; i < end; i += 256)
        atomicAdd(&lcnt[rows[i] >> 7], 1);
    __syncthreads();
    for (int b = threadIdx.x; b < NB; b += 256) {
        int c = lcnt[b];
        lbase[b] = c ? atomicAdd(&bcur[b], c) : 0;
        lcnt[b] = 0;
    }
    __syncthreads();
    for (int i = start + threadIdx.x; i < end; i += 256) {
        int r = rows[i];
        int b = r >> 7;
        int off = atomicAdd(&lcnt[b], 1);
        tmp[lbase[b] + off] = make_int2(cols[i] | ((r & 127) << 17), __float_as_int(vals[i]));
    }
}

// one block per bucket: local row-count + scan -> writes rowptr AND places edges
__global__ __launch_bounds__(256)
void csr_place(const int2* __restrict__ tmp, const int* __restrict__ bbase,
               int* __restrict__ rowptr, int2* __restrict__ packed, int M, int NB)
{
    __shared__ int lcnt[128];
    __shared__ int lofs[128];
    const int tid = threadIdx.x;
    const int b = blockIdx.x;
    const int s = bbase[b], e = bbase[b + 1];
    const int rb = b << 7;
    if (tid < 128) lcnt[tid] = 0;
    __syncthreads();
    for (int i = s + tid; i < e; i += 256)
        atomicAdd(&lcnt[(((unsigned)tmp[i].x) >> 17) & 127], 1);
    __syncthreads();
    if (tid == 0) {
        int run = s;
#pragma unroll 8
        for (int r = 0; r < 128; r++) { lofs[r] = run; run += lcnt[r]; }
    }
    __syncthreads();
    if (tid < 128 && rb + tid < M) rowptr[rb + tid] = lofs[tid];
    if (b == NB - 1 && tid == 0) rowptr[M] = e;
    if (tid < 128) lcnt[tid] = 0;
    __syncthreads();
    for (int i = s + tid; i < e; i += 256) {
        int2 t = tmp[i];
        int rl = (((unsigned)t.x) >> 17) & 127;
        int pos = lofs[rl] + atomicAdd(&lcnt[rl], 1);
        packed[pos] = make_int2(t.x & 0x1FFFF, t.y);
    }
}

// ============ CSR SpMM: 16 lanes/edge x 4 edge-groups, 16B gathers ============
__global__ __launch_bounds__(256)
void spmm_csr(const int* __restrict__ rowptr, const int2* __restrict__ packed,
              const unsigned short* __restrict__ embb, unsigned short* __restrict__ hb, int N)
{
    const int wv = threadIdx.x >> 6, lane = threadIdx.x & 63;
    const int g = lane >> 4, q = lane & 15;
    const int r = blockIdx.x * 4 + wv;
    if (r >= N) return;
    const int s = rowptr[r], e = rowptr[r + 1];
    const unsigned short* __restrict__ eb = embb + q * 8;

    float a0=0.f,a1=0.f,a2=0.f,a3=0.f,a4=0.f,a5=0.f,a6=0.f,a7=0.f;
    int i = s + g;
    for (; i + 12 < e; i += 16) {          // 4 edges per group per pass (16 in flight/wave)
#pragma unroll
        for (int u = 0; u < 4; u++) {
            int2 p = packed[i + 4 * u];
            uint4 m = *(const uint4*)(eb + ((size_t)p.x << 7));
            float v = __int_as_float(p.y);
            a0 += v * __uint_as_float(m.x << 16);
            a1 += v * __uint_as_float(m.x & 0xffff0000u);
            a2 += v * __uint_as_float(m.y << 16);
            a3 += v * __uint_as_float(m.y & 0xffff0000u);
            a4 += v * __uint_as_float(m.z << 16);
            a5 += v * __uint_as_float(m.z & 0xffff0000u);
            a6 += v * __uint_as_float(m.w << 16);
            a7 += v * __uint_as_float(m.w & 0xffff0000u);
        }
    }
    for (; i < e; i += 4) {
        int2 p = packed[i];
        uint4 m = *(const uint4*)(eb + ((size_t)p.x << 7));
        float v = __int_as_float(p.y);
        a0 += v * __uint_as_float(m.x << 16);
        a1 += v * __uint_as_float(m.x & 0xffff0000u);
        a2 += v * __uint_as_float(m.y << 16);
        a3 += v * __uint_as_float(m.y & 0xffff0000u);
        a4 += v * __uint_as_float(m.z << 16);
        a5 += v * __uint_as_float(m.z & 0xffff0000u);
        a6 += v * __uint_as_float(m.w << 16);
        a7 += v * __uint_as_float(m.w & 0xffff0000u);
    }
#pragma unroll
    for (int msk = 16; msk <= 32; msk <<= 1) {
        a0 += __shfl_xor(a0, msk); a1 += __shfl_xor(a1, msk);
        a2 += __shfl_xor(a2, msk); a3 += __shfl_xor(a3, msk);
        a4 += __shfl_xor(a4, msk); a5 += __shfl_xor(a5, msk);
        a6 += __shfl_xor(a6, msk); a7 += __shfl_xor(a7, msk);
    }
    if (g == 0) {
        unsigned o0 = (unsigned)f2bf(a0) | ((unsigned)f2bf(a1) << 16);
        unsigned o1 = (unsigned)f2bf(a2) | ((unsigned)f2bf(a3) << 16);
        unsigned o2 = (unsigned)f2bf(a4) | ((unsigned)f2bf(a5) << 16);
        unsigned o3 = (unsigned)f2bf(a6) | ((unsigned)f2bf(a7) << 16);
        *(uint4*)(hb + ((size_t)r << 7) + q * 8) = make_uint4(o0, o1, o2, o3);
    }
}

// ============ launch ============
extern "C" void kernel_launch(void* const* d_in, const int* in_sizes, int n_in,
                              void* d_out, int out_size, void* d_ws, size_t ws_size,
                              hipStream_t stream)
{
    const float* feat  = (const float*)d_in[0];
    const int*   srows = (const int*)  d_in[1];
    const int*   scols = (const int*)  d_in[2];
    const float* svals = (const float*)d_in[3];
    const float* Wf0   = (const float*)d_in[4];
    const float* bf0   = (const float*)d_in[5];
    const float* Wf1   = (const float*)d_in[6];
    const float* bf1   = (const float*)d_in[7];
    const float* Wg    = (const float*)d_in[8];
    const float* Wemb  = (const float*)d_in[9];
    const float* bemb  = (const float*)d_in[10];
    const float* Wl    = (const float*)d_in[11];
    const float* bl    = (const float*)d_in[12];
    const float* Wr    = (const float*)d_in[13];
    const float* br    = (const float*)d_in[14];

    const int M = in_sizes[0] / 512;   // 100000 nodes
    const int E = in_sizes[1];         // 3200000 edges
    const int NB = (M + 127) >> 7;     // 782 buckets

    float* out = (float*)d_out;
    float* R0 = out;                        // emb final
    float* R1 = out + (size_t)M * 128;      // lft final
    float* R2 = out + (size_t)M * 256;      // rgt final

    // ---- ws layout ----
    float* ws = (float*)d_ws;
    float* accf = ws;                                      // [M,128] f32 gnn_acc; tmp aliases
    int2*  tmp  = (int2*)ws;                               // [E] int2, dead before s4
    int*   ip = (int*)(ws + (size_t)M * 128);
    int*   rowptr  = ip;                                   // M+1
    int2*  packed  = (int2*)(ip + (((size_t)M + 4) & ~(size_t)3));  // E
    int*   tilesum = (int*)(packed + E);                   // 64
    int*   bcnt    = tilesum + 64;                         // NB
    int*   bbase   = bcnt + 1024;                          // NB+1
    int*   bcur    = bbase + 1032;                         // NB
    unsigned short* Wt0   = (unsigned short*)(bcur + 1024);    // [256][512]
    unsigned short* Wt1   = Wt0 + 256 * 512;                   // [128][256]
    unsigned short* Wg0t  = Wt1 + 128 * 256;                   // 7x [128][128]
    unsigned short* Wg1t  = Wg0t + 16384;
    unsigned short* Wembt = Wg1t + 16384;
    unsigned short* Wl0t  = Wembt + 16384;
    unsigned short* Wl1t  = Wl0t + 16384;
    unsigned short* Wr0t  = Wl1t + 16384;
    unsigned short* Wr1t  = Wr0t + 16384;

    // ---- d_out scratch timeline ----
    unsigned short* R0a = (unsigned short*)R0;
    unsigned short* R0b = (unsigned short*)R0 + (size_t)M * 128;
    unsigned short* R1a = (unsigned short*)R1;
    unsigned short* feat_bf = (unsigned short*)R0;  // [M,512] = R0+R1, dead after s1
    unsigned short* x1_bf   = (unsigned short*)R2;  // [M,256], dead after s2
    unsigned short* x_bf    = R0a;                  // s2 out; spmm3 src; s4 aux (feat_bf dead)
    unsigned short* h_bf    = R0b;                  // spmm3->s4 ; spmm5->s6
    unsigned short* n0_bf   = R1a;                  // s4 -> spmm5
    unsigned short* n1_bf   = R0a;                  // s6 -> s10/s8 (x_bf dead)
    unsigned short* rgt0_bf = R1a;                  // s10 -> s11 (n0 dead)
    unsigned short* lft0_bf = R0b;                  // s8 -> s9 (h dead)

    dim3 blk(256);
    const int gm128 = (M + 127) / 128;
    const int nch   = (E + RCHUNK - 1) / RCHUNK;

    // weight converts
    wconv<<<(512*256 + 255)/256, blk, 0, stream>>>(Wf0, Wt0, 512, 256);
    wconv<<<(256*128 + 255)/256, blk, 0, stream>>>(Wf1, Wt1, 256, 128);
    wconv<<<64, blk, 0, stream>>>(Wg,          Wg0t,  128, 128);
    wconv<<<64, blk, 0, stream>>>(Wg + 16384,  Wg1t,  128, 128);
    wconv<<<64, blk, 0, stream>>>(Wemb,        Wembt, 128, 128);
    wconv<<<64, blk, 0, stream>>>(Wl,          Wl0t,  128, 128);
    wconv<<<64, blk, 0, stream>>>(Wl + 16384,  Wl1t,  128, 128);
    wconv<<<64, blk, 0, stream>>>(Wr,          Wr0t,  128, 128);
    wconv<<<64, blk, 0, stream>>>(Wr + 16384,  Wr1t,  128, 128);

    // feat -> bf16 (into R0+R1; streams at HBM BW)
    f32_to_bf16<<<(int)(((long)M * 64 + 255) / 256), blk, 0, stream>>>(feat, feat_bf, (long)M * 64);

    // ---- CSR build: bucket pass + fused rowptr/place ----
    hipMemsetAsync(bcnt, 0, (size_t)NB * 4, stream);
    bhist_k<<<nch, blk, 0, stream>>>(srows, bcnt, E, NB);
    scan_phaseA<<<1, blk, 0, stream>>>(bcnt, tilesum, NB);
    scan_phaseB<<<1, 64, 0, stream>>>(tilesum, bbase, 1, NB);
    scan_phaseC<<<1, blk, 0, stream>>>(bcnt, tilesum, bbase, NB);
    init_bcur<<<(NB + 255)/256, blk, 0, stream>>>(bbase, bcur, NB);
    bucket_scatter<<<nch, blk, 0, stream>>>(srows, scols, svals, bcur, tmp, E, NB);
    csr_place<<<NB, blk, 0, stream>>>(tmp, bbase, rowptr, packed, M, NB);

    // ---- network ----
    // s1: x1_bf = tanh(feat @ Wf0 + bf0)
    mfma_direct<<<dim3(gm128,2),blk,0,stream>>>(feat_bf, Wt0, bf0, x1_bf, M, 512, 256);
    // s2: x_bf = tanh(x1 @ Wf1 + bf1)
    mfma_direct<<<dim3(gm128,1),blk,0,stream>>>(x1_bf, Wt1, bf1, x_bf, M, 256, 128);
    // spmm3: h_bf = S @ x
    spmm_csr<<<(M + 3) / 4, blk, 0, stream>>>(rowptr, packed, x_bf, h_bf, M);
    // s4: n0 = l2norm(tanh(h @ Wg0)) -> n0_bf; accf = x + n0
    mfma_ep<true,true,true,false,true,true,false,true,false><<<gm128,blk,0,stream>>>(
        h_bf, Wg0t, nullptr, nullptr, x_bf, accf, nullptr, n0_bf, M);
    // spmm5: h_bf = S @ n0
    spmm_csr<<<(M + 3) / 4, blk, 0, stream>>>(rowptr, packed, n0_bf, h_bf, M);
    // s6: n1 = l2norm(tanh(h @ Wg1)) -> n1_bf; accf += n1 (in-place)
    mfma_ep<true,true,true,false,true,false,false,true,false><<<gm128,blk,0,stream>>>(
        h_bf, Wg1t, nullptr, nullptr, accf, accf, nullptr, n1_bf, M);
    // s10: rgt0 = tanh(n1 @ Wr0 + br0) + n1 -> rgt0_bf
    mfma_ep<true,true,false,true,false,false,false,true,true><<<gm128,blk,0,stream>>>(
        n1_bf, Wr0t, br, n1_bf, nullptr, nullptr, nullptr, rgt0_bf, M);
    // s11: rgt = tanh(rgt0 @ Wr1 + br1) -> R2 final
    mfma_ep<true,true,false,false,false,false,true,false,true><<<gm128,blk,0,stream>>>(
        rgt0_bf, Wr1t, br + 128, nullptr, nullptr, nullptr, R2, nullptr, M);
    // s8: lft0 = tanh(n1 @ Wl0 + bl0) + n1 -> lft0_bf
    mfma_ep<true,true,false,true,false,false,false,true,true><<<gm128,blk,0,stream>>>(
        n1_bf, Wl0t, bl, n1_bf, nullptr, nullptr, nullptr, lft0_bf, M);
    // s9: lft = tanh(lft0 @ Wl1 + bl1) -> R1 final
    mfma_ep<true,true,false,false,false,false,true,false,true><<<gm128,blk,0,stream>>>(
        lft0_bf, Wl1t, bl + 128, nullptr, nullptr, nullptr, R1, nullptr, M);
    // s7: emb = l2norm(accf @ Wemb + bemb) -> R0 final (last: frees R0 scratch)
    mfma_ep<false,false,true,false,false,false,true,false,true><<<gm128,blk,0,stream>>>(
        accf, Wembt, bemb, nullptr, nullptr, nullptr, R0, nullptr, M);
}